// Round 4
// baseline (163.624 us; speedup 1.0000x reference)
//
#include <hip/hip_runtime.h>
#include <hip/hip_bf16.h>
#include <cstddef>

// Problem constants
#define BATCH 2
#define SEQ   2048
#define DM    768
#define NH    12
#define HD    64
#define N3    2304      // 3*DM
#define NKV   1536      // 2*DM (K,V cols)
#define KSEL  46        // ceil(sqrt(2048))
#define NROW  (BATCH*KSEL)  // 92
#define NCHUNK 32       // 2048/64

typedef unsigned short ushort_t;
typedef __attribute__((ext_vector_type(8))) short bf16x8;
typedef __attribute__((ext_vector_type(4))) float f32x4;

__device__ __forceinline__ ushort_t f2bf(float f) {
  union { __hip_bfloat16 h; ushort_t u; } cv;
  cv.h = __float2bfloat16(f);
  return cv.u;
}
__device__ __forceinline__ float bf2f(ushort_t u) {
  union { unsigned int i; float f; } cv;
  cv.i = ((unsigned int)u) << 16;
  return cv.f;
}

#define GLD16(g, l)                                                         \
  __builtin_amdgcn_global_load_lds(                                         \
      (const __attribute__((address_space(1))) void*)(g),                   \
      (__attribute__((address_space(3))) void*)(l), 16, 0, 0)

// ---------------------------------------------------------------------------
// prep: fused single-pass row kernel (cast x + y=x copy + sel logits: x read
// ONCE, 1024 blocks) + full-Wqkv transpose (1728) + WoT (576).
// Total 3328 blocks.
// ---------------------------------------------------------------------------
__global__ __launch_bounds__(256) void prep_kernel(
    const float* __restrict__ x, const float* __restrict__ W,
    const float* __restrict__ Wo,
    const float* __restrict__ sel_w, const float* __restrict__ sel_b,
    const float* __restrict__ temp,
    ushort_t* __restrict__ xb, ushort_t* __restrict__ Wt,
    ushort_t* __restrict__ WoT,
    float* __restrict__ sel, float* __restrict__ y) {
  const int bx = blockIdx.x;
  const int tid = threadIdx.x;
  if (bx < 1024) {
    // one wave per row: read x once -> {y copy, bf16 cast, sel logits}
    const int w = tid >> 6, lane = tid & 63;
    const int row = bx * 4 + w;
    const float4* xr4 = (const float4*)(x + (size_t)row * DM);
    float4* yr4 = (float4*)(y + (size_t)row * DM);
    ushort4* xb4 = (ushort4*)(xb + (size_t)row * DM);
    const float4* sw4 = (const float4*)sel_w;
    float a0 = 0.f, a1 = 0.f;
#pragma unroll
    for (int i = 0; i < 3; ++i) {
      const int p = i * 64 + lane;          // float4 index within row
      float4 f = xr4[p];
      yr4[p] = f;
      ushort4 o;
      o.x = f2bf(f.x); o.y = f2bf(f.y); o.z = f2bf(f.z); o.w = f2bf(f.w);
      xb4[p] = o;
      // sel_w is [768][2] row-major; float4 pair covers k=4p..4p+3
      float4 sa = sw4[p * 2];
      float4 sb = sw4[p * 2 + 1];
      a0 += f.x * sa.x + f.y * sa.z + f.z * sb.x + f.w * sb.z;
      a1 += f.x * sa.y + f.y * sa.w + f.z * sb.y + f.w * sb.w;
    }
    for (int off = 32; off; off >>= 1) {
      a0 += __shfl_xor(a0, off);
      a1 += __shfl_xor(a1, off);
    }
    if (lane == 0) {
      float t = temp[0];
      float l0 = (a0 + sel_b[0]) / t;
      float l1 = (a1 + sel_b[1]) / t;
      sel[row] = 1.0f / (1.0f + expf(l0 - l1));
    }
  } else if (bx < 2752) {
    // Wt[n][k] = bf16(W[k][n]), all 2304 cols; 32x32 tiles
    __shared__ float tile[32][33];
    const int bx2 = bx - 1024;
    const int n0 = (bx2 % 72) * 32, k0 = (bx2 / 72) * 32;
    const int r = tid >> 3, c4 = (tid & 7) * 4;
    float4 f = *(const float4*)&W[(size_t)(k0 + r) * N3 + n0 + c4];
    tile[r][c4] = f.x; tile[r][c4 + 1] = f.y; tile[r][c4 + 2] = f.z; tile[r][c4 + 3] = f.w;
    __syncthreads();
    ushort4 o;
    o.x = f2bf(tile[c4 + 0][r]);
    o.y = f2bf(tile[c4 + 1][r]);
    o.z = f2bf(tile[c4 + 2][r]);
    o.w = f2bf(tile[c4 + 3][r]);
    *(ushort4*)&Wt[(size_t)(n0 + r) * DM + k0 + c4] = o;
  } else {
    // WoT[n][k] = bf16(Wo[k][n]); 32x32 tiles
    __shared__ float tile2[32][33];
    const int bx3 = bx - 2752;
    const int n0 = (bx3 % 24) * 32, k0 = (bx3 / 24) * 32;
    const int r = tid >> 3, c4 = (tid & 7) * 4;
    float4 f = *(const float4*)&Wo[(size_t)(k0 + r) * DM + n0 + c4];
    tile2[r][c4] = f.x; tile2[r][c4 + 1] = f.y; tile2[r][c4 + 2] = f.z; tile2[r][c4 + 3] = f.w;
    __syncthreads();
    ushort4 o;
    o.x = f2bf(tile2[c4 + 0][r]);
    o.y = f2bf(tile2[c4 + 1][r]);
    o.z = f2bf(tile2[c4 + 2][r]);
    o.w = f2bf(tile2[c4 + 3][r]);
    *(ushort4*)&WoT[(size_t)(n0 + r) * DM + k0 + c4] = o;
  }
}

// ---------------------------------------------------------------------------
// top-46 per batch via radix select on float bits (sel >= 0 -> monotone).
// grid 2 x 256.  Wave-shuffle suffix scan (5 barriers/pass).
// Emits the selected set in ASCENDING index order (deterministic; also gives
// monotone gather locality downstream).  Ties keep lowest indices, matching
// jax.lax.top_k's selected SET.  Writes idx[b*46+j] and padded idxp[b*64+j].
// ---------------------------------------------------------------------------
__global__ __launch_bounds__(256) void topk_kernel(
    const float* __restrict__ sel, int* __restrict__ idx,
    int* __restrict__ idxp) {
  __shared__ unsigned int hist[256];
  __shared__ unsigned int cum[256];
  __shared__ unsigned int wtot[4];
  __shared__ int sh_b;
  __shared__ int c_gt, c_eq;
  __shared__ int tmp_gt[KSEL];
  __shared__ int eqlist[256];
  __shared__ int fin[64];
  __shared__ int srt[64];
  const int b = blockIdx.x, tid = threadIdx.x;
  const int lane = tid & 63, w = tid >> 6;

  unsigned int key[8];
  int  kidx[8];
#pragma unroll
  for (int e = 0; e < 8; ++e) {
    int i = e * 256 + tid;
    kidx[e] = i;
    key[e] = __float_as_uint(sel[b * SEQ + i]);
  }
  unsigned int prefix = 0, mask = 0;
  int r = KSEL;
#pragma unroll
  for (int p = 3; p >= 0; --p) {
    const int shift = 8 * p;
    hist[tid] = 0;
    __syncthreads();
#pragma unroll
    for (int e = 0; e < 8; ++e)
      if ((key[e] & mask) == prefix)
        atomicAdd(&hist[(key[e] >> shift) & 255], 1u);
    __syncthreads();
    unsigned int v = hist[tid];
#pragma unroll
    for (int off = 1; off < 64; off <<= 1) {
      unsigned int t = __shfl_down(v, off);
      if (lane + off < 64) v += t;
    }
    if (lane == 0) wtot[w] = v;
    __syncthreads();
    unsigned int addhi = 0;
    for (int ww = w + 1; ww < 4; ++ww) addhi += wtot[ww];
    v += addhi;
    cum[tid] = v;
    __syncthreads();
    if (v >= (unsigned int)r && (tid == 255 || cum[tid + 1] < (unsigned int)r))
      sh_b = tid;
    __syncthreads();
    const int bsel = sh_b;
    r -= (bsel == 255) ? 0 : (int)cum[bsel + 1];
    prefix |= ((unsigned int)bsel) << shift;
    mask |= 0xFFu << shift;
    __syncthreads();
  }
  // T = prefix; select all > T, plus r lowest-index == T
  if (tid == 0) { c_gt = 0; c_eq = 0; }
  __syncthreads();
#pragma unroll
  for (int e = 0; e < 8; ++e) {
    if (key[e] > prefix) {
      int pos = atomicAdd(&c_gt, 1);
      tmp_gt[pos] = kidx[e];
    } else if (key[e] == prefix) {
      int pos = atomicAdd(&c_eq, 1);
      if (pos < 256) eqlist[pos] = kidx[e];
    }
  }
  __syncthreads();
  if (tid == 0) {
    const int need = KSEL - c_gt;
    const int ec = (c_eq < 256) ? c_eq : 256;
    for (int a = 0; a < need; ++a) {       // selection of smallest indices
      int mb = a;
      for (int bb = a + 1; bb < ec; ++bb)
        if (eqlist[bb] < eqlist[mb]) mb = bb;
      int tv = eqlist[a]; eqlist[a] = eqlist[mb]; eqlist[mb] = tv;
    }
  }
  __syncthreads();
  if (tid < KSEL)
    fin[tid] = (tid < c_gt) ? tmp_gt[tid] : eqlist[tid - c_gt];
  __syncthreads();
  if (tid < KSEL) {
    const int v = fin[tid];
    int rank = 0;
    for (int j = 0; j < KSEL; ++j) rank += (fin[j] < v);
    srt[rank] = v;   // indices distinct -> ranks unique
  }
  __syncthreads();
  if (tid < 64) {
    if (tid < KSEL) {
      idx[b * KSEL + tid] = srt[tid];
      idxp[b * 64 + tid] = srt[tid];
    } else {
      idxp[b * 64 + tid] = 0;
    }
  }
}

// ---------------------------------------------------------------------------
// Q-projection GEMM (bf16 MFMA, 6 blocks):
//   qb[128,768] = Xbf[gathered rows] @ Wt[0:768]^T + bias
// 128x128 tile, BK=32, 4 waves each 64x64.
// ---------------------------------------------------------------------------
__global__ __launch_bounds__(256) void qgemm_kernel(
    const ushort_t* __restrict__ Xbf,   // [4096][768]
    const ushort_t* __restrict__ Wt,    // [2304][768]
    const float* __restrict__ bias,     // 2304 (use cols 0..768)
    const int* __restrict__ idxp,       // [128] padded selected rows
    ushort_t* __restrict__ qb) {        // [128][768] bf16
  __shared__ ushort_t As[128 * 32];
  __shared__ ushort_t Bs[128 * 32];
  const int tid = threadIdx.x;
  const int lane = tid & 63, w = tid >> 6;
  const int wr = w >> 1, wc = w & 1;
  const int quad = lane >> 4, l16 = lane & 15;
  const int ci0 = tid;
  const int ci1 = 256 + tid;
  const int n0 = blockIdx.x * 128;
  const int r0 = ci0 >> 2, r1 = ci1 >> 2;
  const size_t ga0 = (size_t)((r0 >> 6) * SEQ + idxp[r0]) * DM;
  const size_t ga1 = (size_t)((r1 >> 6) * SEQ + idxp[r1]) * DM;
  const size_t gb0 = (size_t)(n0 + r0) * DM;
  const size_t gb1 = (size_t)(n0 + r1) * DM;
  const int ka0 = (ci0 & 3) * 8, ka1 = (ci1 & 3) * 8;

  f32x4 acc[4][4] = {};
  for (int k0 = 0; k0 < DM; k0 += 32) {
    GLD16(Xbf + ga0 + k0 + ka0, &As[(w * 64) * 8]);
    GLD16(Xbf + ga1 + k0 + ka1, &As[(256 + w * 64) * 8]);
    GLD16(Wt + gb0 + k0 + ka0, &Bs[(w * 64) * 8]);
    GLD16(Wt + gb1 + k0 + ka1, &Bs[(256 + w * 64) * 8]);
    __syncthreads();
    bf16x8 af[4], bfr[4];
#pragma unroll
    for (int i = 0; i < 4; ++i)
      af[i] = *(const bf16x8*)&As[(wr * 64 + i * 16 + l16) * 32 + quad * 8];
#pragma unroll
    for (int j = 0; j < 4; ++j)
      bfr[j] = *(const bf16x8*)&Bs[(wc * 64 + j * 16 + l16) * 32 + quad * 8];
#pragma unroll
    for (int i = 0; i < 4; ++i)
#pragma unroll
      for (int j = 0; j < 4; ++j)
        acc[i][j] = __builtin_amdgcn_mfma_f32_16x16x32_bf16(af[i], bfr[j], acc[i][j], 0, 0, 0);
    __syncthreads();
  }
#pragma unroll
  for (int i = 0; i < 4; ++i) {
    const int row_base = wr * 64 + i * 16 + quad * 4;
#pragma unroll
    for (int j = 0; j < 4; ++j) {
      const int col = n0 + wc * 64 + j * 16 + l16;
      const float bv = bias[col];
#pragma unroll
      for (int r = 0; r < 4; ++r)
        qb[(size_t)(row_base + r) * DM + col] = f2bf(acc[i][j][r] + bv);
    }
  }
}

// ---------------------------------------------------------------------------
// Fused K/V-projection + attention chunk kernel: grid (32 c, 12 h, 2 b),
// 256 thr = 4 waves.  Each block computes its OWN K-chunk and V-chunk
// (64 keys x 64 dims each, K=768) straight into LDS -- no kv materialization
// (zero redundant FLOPs: each (key,head) projection has exactly one consumer).
//   K-proj: A=weights B=X  -> thread holds (dim, key) -> Kc[key][dim] ushort4
//   V-proj: A=X B=weights  -> thread holds (key, dim) -> Vt[dim][key] ushort4
// Then S = Q K^T (Q from qb), per-chunk softmax, PV, bf16 partial O --
// numerically identical to the old kv-GEMM path (same MFMA order, same
// bias-then-bf16 rounding).
// ---------------------------------------------------------------------------
__global__ __launch_bounds__(256) void attn_chunk_kernel(
    const ushort_t* __restrict__ Xbf,  // [4096][768] bf16
    const ushort_t* __restrict__ Wt,   // [2304][768] bf16
    const float* __restrict__ bias,    // 2304 (K: 768.., V: 1536..)
    const ushort_t* __restrict__ qb,   // [128][768] bf16
    const int* __restrict__ idx,
    float* __restrict__ m_part, float* __restrict__ l_part,
    ushort_t* __restrict__ o_part) {
  __shared__ ushort_t As[64 * 32];          // X chunk rows, BK=32
  __shared__ ushort_t Bs[128 * 32];         // [K-weights 64 | V-weights 64]
  __shared__ __align__(16) ushort_t Kc[64][72];
  __shared__ __align__(16) ushort_t Vt[64][72];
  __shared__ __align__(16) ushort_t Ps[4][16][72];
  __shared__ int tS[64];
  __shared__ int tmaxS;
  const int tid = threadIdx.x;
  const int c = blockIdx.x, h = blockIdx.y, b = blockIdx.z;
  const int c0 = c * 64;
  if (tid < 64) {
    int t = (tid < KSEL) ? idx[b * KSEL + tid] : -1;
    tS[tid] = t;
    int tm = t;
    for (int off = 32; off; off >>= 1) tm = max(tm, __shfl_xor(tm, off));
    if (tid == 0) tmaxS = tm;
  }
  __syncthreads();
  if (c0 > tmaxS) return;   // uniform across block (skips proj work too)

  const int lane = tid & 63, w = tid >> 6;
  const int quad = lane >> 4, l16 = lane & 15;

  // ---- K/V projection into LDS ----
  const int arow = tid >> 2;                 // 0..63
  const int ka = (tid & 3) * 8;
  const size_t gax = (size_t)(b * SEQ + c0 + arow) * DM;        // X rows
  const size_t gbk = (size_t)(768 + h * HD + arow) * DM;        // K-weight rows
  const size_t gbv = (size_t)(1536 + h * HD + arow) * DM;       // V-weight rows

  f32x4 accK[4] = {}, accV[4] = {};
  for (int k0 = 0; k0 < DM; k0 += 32) {
    GLD16(Xbf + gax + k0 + ka, &As[(w * 64) * 8]);
    GLD16(Wt + gbk + k0 + ka, &Bs[(w * 64) * 8]);
    GLD16(Wt + gbv + k0 + ka, &Bs[(256 + w * 64) * 8]);
    __syncthreads();
    bf16x8 aK = *(const bf16x8*)&Bs[(w * 16 + l16) * 32 + quad * 8];       // dims
    bf16x8 aV = *(const bf16x8*)&As[(w * 16 + l16) * 32 + quad * 8];       // keys
#pragma unroll
    for (int j = 0; j < 4; ++j) {
      bf16x8 bX = *(const bf16x8*)&As[(j * 16 + l16) * 32 + quad * 8];     // keys
      bf16x8 bW = *(const bf16x8*)&Bs[(64 * 32) + (j * 16 + l16) * 32 + quad * 8]; // vdims
      accK[j] = __builtin_amdgcn_mfma_f32_16x16x32_bf16(aK, bX, accK[j], 0, 0, 0);
      accV[j] = __builtin_amdgcn_mfma_f32_16x16x32_bf16(aV, bW, accV[j], 0, 0, 0);
    }
    __syncthreads();
  }
  // epilogue: K -> Kc[key][dim], V -> Vt[dim][key]  (both ushort4)
  {
    float bK[4];
#pragma unroll
    for (int r = 0; r < 4; ++r) bK[r] = bias[768 + h * HD + w * 16 + quad * 4 + r];
#pragma unroll
    for (int j = 0; j < 4; ++j) {
      ushort4 ok;
      ok.x = f2bf(accK[j][0] + bK[0]);
      ok.y = f2bf(accK[j][1] + bK[1]);
      ok.z = f2bf(accK[j][2] + bK[2]);
      ok.w = f2bf(accK[j][3] + bK[3]);
      *(ushort4*)&Kc[j * 16 + l16][w * 16 + quad * 4] = ok;
      const float bV = bias[1536 + h * HD + j * 16 + l16];
      ushort4 ov;
      ov.x = f2bf(accV[j][0] + bV);
      ov.y = f2bf(accV[j][1] + bV);
      ov.z = f2bf(accV[j][2] + bV);
      ov.w = f2bf(accV[j][3] + bV);
      *(ushort4*)&Vt[j * 16 + l16][w * 16 + quad * 4] = ov;
    }
  }
  __syncthreads();

  // ---- S = Q K^T ----
  const ushort_t* qsrc = qb + (size_t)(b * 64 + w * 16 + l16) * DM + h * HD + quad * 8;
  bf16x8 aq0 = *(const bf16x8*)&qsrc[0];
  bf16x8 aq1 = *(const bf16x8*)&qsrc[32];

  f32x4 acc[4] = {};
#pragma unroll
  for (int nt = 0; nt < 4; ++nt) {
    bf16x8 bk0 = *(const bf16x8*)&Kc[nt * 16 + l16][quad * 8];
    bf16x8 bk1 = *(const bf16x8*)&Kc[nt * 16 + l16][32 + quad * 8];
    acc[nt] = __builtin_amdgcn_mfma_f32_16x16x32_bf16(aq0, bk0, acc[nt], 0, 0, 0);
    acc[nt] = __builtin_amdgcn_mfma_f32_16x16x32_bf16(aq1, bk1, acc[nt], 0, 0, 0);
  }

  // per-chunk softmax
  float p[4][4];
  float mrow[4], lrow[4];
#pragma unroll
  for (int r = 0; r < 4; ++r) {
    const int q = w * 16 + quad * 4 + r;
    const int t = tS[q];
    float mx = -1e30f;
#pragma unroll
    for (int nt = 0; nt < 4; ++nt) {
      float s = acc[nt][r] * 0.125f;
      if (c0 + nt * 16 + l16 > t) s = -1e30f;
      p[nt][r] = s;
      mx = fmaxf(mx, s);
    }
#pragma unroll
    for (int off = 1; off < 16; off <<= 1) mx = fmaxf(mx, __shfl_xor(mx, off));
    float sum = 0.f;
#pragma unroll
    for (int nt = 0; nt < 4; ++nt) {
      float pv = __expf(p[nt][r] - mx);
      p[nt][r] = pv;
      sum += pv;
    }
#pragma unroll
    for (int off = 1; off < 16; off <<= 1) sum += __shfl_xor(sum, off);
    mrow[r] = mx; lrow[r] = sum;
  }

  const size_t pbase = ((size_t)(b * NH + h) * NCHUNK + c) * 64;
  if (l16 == 0) {
#pragma unroll
    for (int r = 0; r < 4; ++r) {
      const int q = w * 16 + quad * 4 + r;
      m_part[pbase + q] = mrow[r];
      l_part[pbase + q] = lrow[r];
    }
  }

  // P -> LDS (A-layout source)
#pragma unroll
  for (int r = 0; r < 4; ++r)
#pragma unroll
    for (int nt = 0; nt < 4; ++nt)
      Ps[w][quad * 4 + r][nt * 16 + l16] = f2bf(p[nt][r]);
  __syncthreads();

  // O = P V
  bf16x8 ap0 = *(const bf16x8*)&Ps[w][l16][quad * 8];
  bf16x8 ap1 = *(const bf16x8*)&Ps[w][l16][32 + quad * 8];
  f32x4 acc2[4] = {};
#pragma unroll
  for (int nt = 0; nt < 4; ++nt) {
    bf16x8 bv0 = *(const bf16x8*)&Vt[nt * 16 + l16][quad * 8];
    bf16x8 bv1 = *(const bf16x8*)&Vt[nt * 16 + l16][32 + quad * 8];
    acc2[nt] = __builtin_amdgcn_mfma_f32_16x16x32_bf16(ap0, bv0, acc2[nt], 0, 0, 0);
    acc2[nt] = __builtin_amdgcn_mfma_f32_16x16x32_bf16(ap1, bv1, acc2[nt], 0, 0, 0);
  }
  ushort_t* obp = o_part + pbase * 64;
#pragma unroll
  for (int nt = 0; nt < 4; ++nt)
#pragma unroll
    for (int r = 0; r < 4; ++r)
      obp[(w * 16 + quad * 4 + r) * 64 + nt * 16 + l16] = f2bf(acc2[nt][r]);
}

// ---------------------------------------------------------------------------
// combine partials -> ctx (bf16, padded [128][768]): grid (3, 12, 2)
// ---------------------------------------------------------------------------
__global__ __launch_bounds__(256) void attn_combine_kernel(
    const float* __restrict__ m_part, const float* __restrict__ l_part,
    const ushort_t* __restrict__ o_part, const int* __restrict__ idx,
    ushort_t* __restrict__ ctx_bf) {
  __shared__ float wgt[NCHUNK][16];
  __shared__ float linv[16];
  __shared__ int ncS[16];
  const int rg = blockIdx.x, h = blockIdx.y, b = blockIdx.z;
  const int tid = threadIdx.x;
  const size_t base = (size_t)(b * NH + h) * NCHUNK * 64;
  if (tid < 16) {
    const int q = rg * 16 + tid;
    float L = 0.f; int nc = 0;
    if (q < KSEL) {
      const int t = idx[b * KSEL + q];
      nc = (t >> 6) + 1;
      float M = -1e30f;
      for (int cc = 0; cc < nc; ++cc)
        M = fmaxf(M, m_part[base + cc * 64 + q]);
      for (int cc = 0; cc < nc; ++cc) {
        float wv = __expf(m_part[base + cc * 64 + q] - M);
        wgt[cc][tid] = wv;
        L += wv * l_part[base + cc * 64 + q];
      }
    }
    ncS[tid] = nc;
    linv[tid] = (L > 0.f) ? 1.0f / L : 0.f;
  }
  __syncthreads();
  const int rl = tid >> 4;
  const int d4 = (tid & 15) * 4;
  const int q = rg * 16 + rl;
  if (q >= KSEL) return;
  const int nc = ncS[rl];
  float4 a = {0.f, 0.f, 0.f, 0.f};
  const ushort_t* obp = o_part + base * 64 + (size_t)q * 64 + d4;
  for (int cc = 0; cc < nc; ++cc) {
    const float wv = wgt[cc][rl];
    const ushort4 ov = *(const ushort4*)&obp[(size_t)cc * 4096];
    a.x += wv * bf2f(ov.x); a.y += wv * bf2f(ov.y);
    a.z += wv * bf2f(ov.z); a.w += wv * bf2f(ov.w);
  }
  const float li = linv[rl];
  ushort4 o;
  o.x = f2bf(a.x * li); o.y = f2bf(a.y * li);
  o.z = f2bf(a.z * li); o.w = f2bf(a.w * li);
  *(ushort4*)&ctx_bf[(size_t)(b * 64 + q) * DM + h * HD + d4] = o;
}

// ---------------------------------------------------------------------------
// out-proj GEMM (bf16 MFMA, 24 blocks): gated = (ctx @ WoT^T + ob) * sel,
// scatter-added straight into y via atomicAdd.
// M=128 (92 valid), N-tile=64 (12 tiles), split-K=2 (384 each).
// Bias added only by the kb==0 block.
// ---------------------------------------------------------------------------
__global__ __launch_bounds__(256) void outproj_kernel(
    const ushort_t* __restrict__ ctx_bf,  // [128][768]
    const ushort_t* __restrict__ WoT,     // [768][768]
    const float* __restrict__ ob, const int* __restrict__ idx,
    const float* __restrict__ sel, float* __restrict__ y) {
  __shared__ ushort_t As[128 * 32];
  __shared__ ushort_t Bs[64 * 32];
  const int tid = threadIdx.x;
  const int lane = tid & 63, w = tid >> 6;
  const int wr = w >> 1, wc = w & 1;
  const int kb = blockIdx.x / 12;          // split-K half
  const int n0 = (blockIdx.x % 12) * 64;   // output-col tile
  const int kbase = kb * 384;
  const int quad = lane >> 4, l16 = lane & 15;
  const int ci0 = tid;
  const int ci1 = 256 + tid;
  const size_t ga0 = (size_t)(ci0 >> 2) * DM;
  const size_t ga1 = (size_t)(ci1 >> 2) * DM;
  const size_t gb0 = (size_t)(n0 + (tid >> 2)) * DM;  // 64 B rows
  const int ka0 = (ci0 & 3) * 8, ka1 = (ci1 & 3) * 8;
  const int kq = (tid & 3) * 8;
  f32x4 acc[4][2] = {};
  for (int k0 = kbase; k0 < kbase + 384; k0 += 32) {
    GLD16(ctx_bf + ga0 + k0 + ka0, &As[(w * 64) * 8]);
    GLD16(ctx_bf + ga1 + k0 + ka1, &As[(256 + w * 64) * 8]);
    GLD16(WoT + gb0 + k0 + kq, &Bs[(w * 16) * 32]);
    __syncthreads();
    bf16x8 af[4], bfr[2];
#pragma unroll
    for (int i = 0; i < 4; ++i)
      af[i] = *(const bf16x8*)&As[(wr * 64 + i * 16 + l16) * 32 + quad * 8];
#pragma unroll
    for (int j = 0; j < 2; ++j)
      bfr[j] = *(const bf16x8*)&Bs[(wc * 32 + j * 16 + l16) * 32 + quad * 8];
#pragma unroll
    for (int i = 0; i < 4; ++i)
#pragma unroll
      for (int j = 0; j < 2; ++j)
        acc[i][j] = __builtin_amdgcn_mfma_f32_16x16x32_bf16(af[i], bfr[j], acc[i][j], 0, 0, 0);
    __syncthreads();
  }
#pragma unroll
  for (int i = 0; i < 4; ++i) {
#pragma unroll
    for (int r = 0; r < 4; ++r) {
      const int row = wr * 64 + i * 16 + quad * 4 + r;
      const int b = row >> 6, jj = row & 63;
      if (jj >= KSEL) continue;
      const int t = idx[b * KSEL + jj];
      const float sv = sel[b * SEQ + t];
      float* yr = y + (size_t)(b * SEQ + t) * DM;
#pragma unroll
      for (int j = 0; j < 2; ++j) {
        const int col = n0 + wc * 32 + j * 16 + l16;
        const float bv = (kb == 0) ? ob[col] : 0.f;
        atomicAdd(&yr[col], (acc[i][j][r] + bv) * sv);
      }
    }
  }
}

// ---------------------------------------------------------------------------
extern "C" void kernel_launch(void* const* d_in, const int* in_sizes, int n_in,
                              void* d_out, int out_size, void* d_ws, size_t ws_size,
                              hipStream_t stream) {
  const float* x      = (const float*)d_in[0];
  const float* Wqkv_w = (const float*)d_in[1];
  const float* Wqkv_b = (const float*)d_in[2];
  const float* sel_w  = (const float*)d_in[3];
  const float* sel_b  = (const float*)d_in[4];
  const float* out_w  = (const float*)d_in[5];
  const float* out_b  = (const float*)d_in[6];
  const float* temp   = (const float*)d_in[7];
  float* y = (float*)d_out;

  // workspace layout (bytes, all 16B aligned)
  char* wsb = (char*)d_ws;
  ushort_t* o_part = (ushort_t*)wsb;  wsb += (size_t)24 * NCHUNK * 64 * 64 * 2;    // 6.29 MB
  float*    m_part = (float*)wsb;     wsb += (size_t)24 * NCHUNK * 64 * 4;
  float*    l_part = (float*)wsb;     wsb += (size_t)24 * NCHUNK * 64 * 4;
  float*    sel    = (float*)wsb;     wsb += (size_t)BATCH * SEQ * 4;
  int*      idx    = (int*)wsb;       wsb += 128 * 4;
  int*      idxp   = (int*)wsb;       wsb += 128 * 4;
  ushort_t* ctx_bf = (ushort_t*)wsb;  wsb += (size_t)128 * DM * 2;
  ushort_t* qb     = (ushort_t*)wsb;  wsb += (size_t)128 * DM * 2;
  ushort_t* Xbf    = (ushort_t*)wsb;  wsb += (size_t)BATCH * SEQ * DM * 2;         // 6.29 MB
  ushort_t* Wt     = (ushort_t*)wsb;  wsb += (size_t)N3 * DM * 2;                  // 3.54 MB
  ushort_t* WoT    = (ushort_t*)wsb;  wsb += (size_t)DM * DM * 2;                  // 1.18 MB

  prep_kernel<<<dim3(3328), 256, 0, stream>>>(x, Wqkv_w, out_w, sel_w, sel_b, temp,
                                              Xbf, Wt, WoT, sel, y);
  topk_kernel<<<dim3(BATCH), 256, 0, stream>>>(sel, idx, idxp);
  qgemm_kernel<<<dim3(6), 256, 0, stream>>>(Xbf, Wt, Wqkv_b, idxp, qb);
  attn_chunk_kernel<<<dim3(NCHUNK, NH, BATCH), 256, 0, stream>>>(Xbf, Wt, Wqkv_b, qb, idx,
                                                                 m_part, l_part, o_part);
  attn_combine_kernel<<<dim3(3, NH, BATCH), 256, 0, stream>>>(m_part, l_part, o_part, idx, ctx_bf);
  outproj_kernel<<<dim3(6 * 4), 256, 0, stream>>>(ctx_bf, WoT, out_b, idx, sel, y);
}

// Round 5
// 156.852 us; speedup vs baseline: 1.0432x; 1.0432x over previous
//
#include <hip/hip_runtime.h>
#include <hip/hip_bf16.h>
#include <cstddef>

// Problem constants
#define BATCH 2
#define SEQ   2048
#define DM    768
#define NH    12
#define HD    64
#define N3    2304      // 3*DM
#define NKV   1536      // 2*DM (K,V cols)
#define KSEL  46        // ceil(sqrt(2048))
#define NROW  (BATCH*KSEL)  // 92
#define NCHUNK 32       // 2048/64

typedef unsigned short ushort_t;
typedef __attribute__((ext_vector_type(8))) short bf16x8;
typedef __attribute__((ext_vector_type(4))) float f32x4;

__device__ __forceinline__ ushort_t f2bf(float f) {
  union { __hip_bfloat16 h; ushort_t u; } cv;
  cv.h = __float2bfloat16(f);
  return cv.u;
}
__device__ __forceinline__ float bf2f(ushort_t u) {
  union { unsigned int i; float f; } cv;
  cv.i = ((unsigned int)u) << 16;
  return cv.f;
}

#define GLD16(g, l)                                                         \
  __builtin_amdgcn_global_load_lds(                                         \
      (const __attribute__((address_space(1))) void*)(g),                   \
      (__attribute__((address_space(3))) void*)(l), 16, 0, 0)

// ---------------------------------------------------------------------------
// prep: fused single-pass row kernel (cast x + y=x copy + sel logits: x read
// ONCE, 1024 blocks) + full-Wqkv transpose (1728) + WoT (576).
// Total 3328 blocks.
// ---------------------------------------------------------------------------
__global__ __launch_bounds__(256) void prep_kernel(
    const float* __restrict__ x, const float* __restrict__ W,
    const float* __restrict__ Wo,
    const float* __restrict__ sel_w, const float* __restrict__ sel_b,
    const float* __restrict__ temp,
    ushort_t* __restrict__ xb, ushort_t* __restrict__ Wt,
    ushort_t* __restrict__ WoT,
    float* __restrict__ sel, float* __restrict__ y) {
  const int bx = blockIdx.x;
  const int tid = threadIdx.x;
  if (bx < 1024) {
    // one wave per row: read x once -> {y copy, bf16 cast, sel logits}
    const int w = tid >> 6, lane = tid & 63;
    const int row = bx * 4 + w;
    const float4* xr4 = (const float4*)(x + (size_t)row * DM);
    float4* yr4 = (float4*)(y + (size_t)row * DM);
    ushort4* xb4 = (ushort4*)(xb + (size_t)row * DM);
    const float4* sw4 = (const float4*)sel_w;
    float a0 = 0.f, a1 = 0.f;
#pragma unroll
    for (int i = 0; i < 3; ++i) {
      const int p = i * 64 + lane;          // float4 index within row
      float4 f = xr4[p];
      yr4[p] = f;
      ushort4 o;
      o.x = f2bf(f.x); o.y = f2bf(f.y); o.z = f2bf(f.z); o.w = f2bf(f.w);
      xb4[p] = o;
      // sel_w is [768][2] row-major; float4 pair covers k=4p..4p+3
      float4 sa = sw4[p * 2];
      float4 sb = sw4[p * 2 + 1];
      a0 += f.x * sa.x + f.y * sa.z + f.z * sb.x + f.w * sb.z;
      a1 += f.x * sa.y + f.y * sa.w + f.z * sb.y + f.w * sb.w;
    }
    for (int off = 32; off; off >>= 1) {
      a0 += __shfl_xor(a0, off);
      a1 += __shfl_xor(a1, off);
    }
    if (lane == 0) {
      float t = temp[0];
      float l0 = (a0 + sel_b[0]) / t;
      float l1 = (a1 + sel_b[1]) / t;
      sel[row] = 1.0f / (1.0f + expf(l0 - l1));
    }
  } else if (bx < 2752) {
    // Wt[n][k] = bf16(W[k][n]), all 2304 cols; 32x32 tiles
    __shared__ float tile[32][33];
    const int bx2 = bx - 1024;
    const int n0 = (bx2 % 72) * 32, k0 = (bx2 / 72) * 32;
    const int r = tid >> 3, c4 = (tid & 7) * 4;
    float4 f = *(const float4*)&W[(size_t)(k0 + r) * N3 + n0 + c4];
    tile[r][c4] = f.x; tile[r][c4 + 1] = f.y; tile[r][c4 + 2] = f.z; tile[r][c4 + 3] = f.w;
    __syncthreads();
    ushort4 o;
    o.x = f2bf(tile[c4 + 0][r]);
    o.y = f2bf(tile[c4 + 1][r]);
    o.z = f2bf(tile[c4 + 2][r]);
    o.w = f2bf(tile[c4 + 3][r]);
    *(ushort4*)&Wt[(size_t)(n0 + r) * DM + k0 + c4] = o;
  } else {
    // WoT[n][k] = bf16(Wo[k][n]); 32x32 tiles
    __shared__ float tile2[32][33];
    const int bx3 = bx - 2752;
    const int n0 = (bx3 % 24) * 32, k0 = (bx3 / 24) * 32;
    const int r = tid >> 3, c4 = (tid & 7) * 4;
    float4 f = *(const float4*)&Wo[(size_t)(k0 + r) * DM + n0 + c4];
    tile2[r][c4] = f.x; tile2[r][c4 + 1] = f.y; tile2[r][c4 + 2] = f.z; tile2[r][c4 + 3] = f.w;
    __syncthreads();
    ushort4 o;
    o.x = f2bf(tile2[c4 + 0][r]);
    o.y = f2bf(tile2[c4 + 1][r]);
    o.z = f2bf(tile2[c4 + 2][r]);
    o.w = f2bf(tile2[c4 + 3][r]);
    *(ushort4*)&WoT[(size_t)(n0 + r) * DM + k0 + c4] = o;
  }
}

// ---------------------------------------------------------------------------
// top-46 per batch via radix select on float bits (sel >= 0 -> monotone).
// grid 2 x 256.  Wave-shuffle suffix scan (5 barriers/pass).
// Emits the selected set in ASCENDING index order (deterministic; monotone
// gather locality downstream).  Ties keep lowest indices, matching
// jax.lax.top_k's selected SET.  Writes idx[b*46+j] and padded idxp[b*64+j].
// ---------------------------------------------------------------------------
__global__ __launch_bounds__(256) void topk_kernel(
    const float* __restrict__ sel, int* __restrict__ idx,
    int* __restrict__ idxp) {
  __shared__ unsigned int hist[256];
  __shared__ unsigned int cum[256];
  __shared__ unsigned int wtot[4];
  __shared__ int sh_b;
  __shared__ int c_gt, c_eq;
  __shared__ int tmp_gt[KSEL];
  __shared__ int eqlist[256];
  __shared__ int fin[64];
  __shared__ int srt[64];
  const int b = blockIdx.x, tid = threadIdx.x;
  const int lane = tid & 63, w = tid >> 6;

  unsigned int key[8];
  int  kidx[8];
#pragma unroll
  for (int e = 0; e < 8; ++e) {
    int i = e * 256 + tid;
    kidx[e] = i;
    key[e] = __float_as_uint(sel[b * SEQ + i]);
  }
  unsigned int prefix = 0, mask = 0;
  int r = KSEL;
#pragma unroll
  for (int p = 3; p >= 0; --p) {
    const int shift = 8 * p;
    hist[tid] = 0;
    __syncthreads();
#pragma unroll
    for (int e = 0; e < 8; ++e)
      if ((key[e] & mask) == prefix)
        atomicAdd(&hist[(key[e] >> shift) & 255], 1u);
    __syncthreads();
    unsigned int v = hist[tid];
#pragma unroll
    for (int off = 1; off < 64; off <<= 1) {
      unsigned int t = __shfl_down(v, off);
      if (lane + off < 64) v += t;
    }
    if (lane == 0) wtot[w] = v;
    __syncthreads();
    unsigned int addhi = 0;
    for (int ww = w + 1; ww < 4; ++ww) addhi += wtot[ww];
    v += addhi;
    cum[tid] = v;
    __syncthreads();
    if (v >= (unsigned int)r && (tid == 255 || cum[tid + 1] < (unsigned int)r))
      sh_b = tid;
    __syncthreads();
    const int bsel = sh_b;
    r -= (bsel == 255) ? 0 : (int)cum[bsel + 1];
    prefix |= ((unsigned int)bsel) << shift;
    mask |= 0xFFu << shift;
    __syncthreads();
  }
  // T = prefix; select all > T, plus r lowest-index == T
  if (tid == 0) { c_gt = 0; c_eq = 0; }
  __syncthreads();
#pragma unroll
  for (int e = 0; e < 8; ++e) {
    if (key[e] > prefix) {
      int pos = atomicAdd(&c_gt, 1);
      tmp_gt[pos] = kidx[e];
    } else if (key[e] == prefix) {
      int pos = atomicAdd(&c_eq, 1);
      if (pos < 256) eqlist[pos] = kidx[e];
    }
  }
  __syncthreads();
  if (tid == 0) {
    const int need = KSEL - c_gt;
    const int ec = (c_eq < 256) ? c_eq : 256;
    for (int a = 0; a < need; ++a) {       // selection of smallest indices
      int mb = a;
      for (int bb = a + 1; bb < ec; ++bb)
        if (eqlist[bb] < eqlist[mb]) mb = bb;
      int tv = eqlist[a]; eqlist[a] = eqlist[mb]; eqlist[mb] = tv;
    }
  }
  __syncthreads();
  if (tid < KSEL)
    fin[tid] = (tid < c_gt) ? tmp_gt[tid] : eqlist[tid - c_gt];
  __syncthreads();
  if (tid < KSEL) {
    const int v = fin[tid];
    int rank = 0;
    for (int j = 0; j < KSEL; ++j) rank += (fin[j] < v);
    srt[rank] = v;   // indices distinct -> ranks unique
  }
  __syncthreads();
  if (tid < 64) {
    if (tid < KSEL) {
      idx[b * KSEL + tid] = srt[tid];
      idxp[b * 64 + tid] = srt[tid];
    } else {
      idxp[b * 64 + tid] = 0;
    }
  }
}

// ---------------------------------------------------------------------------
// Fused GEMM (bf16 MFMA), 780 blocks of 128x64 tiles (BK=32, 4 waves, each
// wave 64x32 -> acc[4][2]):
//   blocks [0,768): kv[4096,1536] = Xbf @ Wt[768:2304]^T + bias  (bf16 out)
//     XCD-chunked swizzle (bid&7)*96 + bid>>3 (bijective: 768 % 8 == 0);
//     n-major within m so each XCD gets 4 A-panels + all B in its L2.
//   blocks [768,780): qb[128,768] = Xbf[gathered rows] @ Wt[0:768]^T + bias
// 780 blocks = 3.05/CU -- removes the 1.5-wave tail of the 128x128 grid.
// Accumulation order per output element identical to the 128x128 version
// (same k-step sequence) -> bit-identical numerics.
// ---------------------------------------------------------------------------
__global__ __launch_bounds__(256) void gemm_kernel(
    const ushort_t* __restrict__ Xbf,   // [4096][768]
    const ushort_t* __restrict__ Wt,    // [2304][768]
    const float* __restrict__ bias,     // 2304
    const int* __restrict__ idxp,       // [128] padded selected rows
    ushort_t* __restrict__ Ckv,         // [4096][1536] bf16
    ushort_t* __restrict__ qb) {        // [128][768] bf16
  __shared__ ushort_t As[128 * 32];
  __shared__ ushort_t Bs[64 * 32];
  const int bid = blockIdx.x;
  const int tid = threadIdx.x;
  const int lane = tid & 63, w = tid >> 6;
  const int wr = w >> 1, wc = w & 1;
  const int quad = lane >> 4, l16 = lane & 15;
  const int ci0 = tid;
  const int ci1 = 256 + tid;
  const bool isQ = (bid >= 768);
  int m0, nw0;                 // nw0 = weight-row base (0..2304)
  size_t ga0, ga1;             // element offsets of this thread's A rows
  if (isQ) {
    m0 = 0;
    nw0 = (bid - 768) * 64;
    const int r0 = ci0 >> 2, r1 = ci1 >> 2;
    ga0 = (size_t)((r0 >> 6) * SEQ + idxp[r0]) * DM;
    ga1 = (size_t)((r1 >> 6) * SEQ + idxp[r1]) * DM;
  } else {
    const int bid2 = (bid & 7) * 96 + (bid >> 3);  // XCD-chunked swizzle
    m0 = (bid2 / 24) * 128;
    nw0 = 768 + (bid2 % 24) * 64;
    ga0 = (size_t)(m0 + (ci0 >> 2)) * DM;
    ga1 = (size_t)(m0 + (ci1 >> 2)) * DM;
  }
  const size_t gb0 = (size_t)(nw0 + (tid >> 2)) * DM;   // 64 B rows
  const int ka0 = (ci0 & 3) * 8, ka1 = (ci1 & 3) * 8;
  const int kq = (tid & 3) * 8;

  f32x4 acc[4][2] = {};
  for (int k0 = 0; k0 < DM; k0 += 32) {
    GLD16(Xbf + ga0 + k0 + ka0, &As[(w * 64) * 8]);
    GLD16(Xbf + ga1 + k0 + ka1, &As[(256 + w * 64) * 8]);
    GLD16(Wt + gb0 + k0 + kq, &Bs[(w * 16) * 32]);
    __syncthreads();
    bf16x8 af[4], bfr[2];
#pragma unroll
    for (int i = 0; i < 4; ++i)
      af[i] = *(const bf16x8*)&As[(wr * 64 + i * 16 + l16) * 32 + quad * 8];
#pragma unroll
    for (int j = 0; j < 2; ++j)
      bfr[j] = *(const bf16x8*)&Bs[(wc * 32 + j * 16 + l16) * 32 + quad * 8];
#pragma unroll
    for (int i = 0; i < 4; ++i)
#pragma unroll
      for (int j = 0; j < 2; ++j)
        acc[i][j] = __builtin_amdgcn_mfma_f32_16x16x32_bf16(af[i], bfr[j], acc[i][j], 0, 0, 0);
    __syncthreads();
  }
#pragma unroll
  for (int i = 0; i < 4; ++i) {
    const int row_base = wr * 64 + i * 16 + quad * 4;
#pragma unroll
    for (int j = 0; j < 2; ++j) {
      const int col = nw0 + wc * 32 + j * 16 + l16;   // weight-row index
      const float bv = bias[col];
      if (isQ) {
#pragma unroll
        for (int r = 0; r < 4; ++r)
          qb[(size_t)(row_base + r) * DM + col] = f2bf(acc[i][j][r] + bv);
      } else {
#pragma unroll
        for (int r = 0; r < 4; ++r)
          Ckv[(size_t)(m0 + row_base + r) * NKV + (col - 768)] = f2bf(acc[i][j][r] + bv);
      }
    }
  }
}

// ---------------------------------------------------------------------------
// attention chunk kernel: grid (32 chunks, 12 h, 2 b), 256 thr = 4 waves.
// S[64x64] via MFMA, per-chunk softmax, PV via MFMA, bf16 partial O.
// ---------------------------------------------------------------------------
__global__ __launch_bounds__(256) void attn_chunk_kernel(
    const ushort_t* __restrict__ kv,   // [4096][1536] bf16
    const ushort_t* __restrict__ qb,   // [128][768] bf16
    const int* __restrict__ idx,
    float* __restrict__ m_part, float* __restrict__ l_part,
    ushort_t* __restrict__ o_part) {
  __shared__ __align__(16) ushort_t Vt[64][72];
  __shared__ __align__(16) ushort_t Ps[4][16][72];
  __shared__ int tS[64];
  __shared__ int tmaxS;
  const int tid = threadIdx.x;
  const int c = blockIdx.x, h = blockIdx.y, b = blockIdx.z;
  const int c0 = c * 64;
  if (tid < 64) {
    int t = (tid < KSEL) ? idx[b * KSEL + tid] : -1;
    tS[tid] = t;
    int tm = t;
    for (int off = 32; off; off >>= 1) tm = max(tm, __shfl_xor(tm, off));
    if (tid == 0) tmaxS = tm;
  }
  __syncthreads();
  if (c0 > tmaxS) return;   // uniform across block

  // stage V transposed: Vt[d][key]
  {
    const int key = tid >> 2, ds0 = (tid & 3) * 16;
    const ushort_t* vsrc = kv + (size_t)(b * SEQ + c0 + key) * NKV + DM + h * HD + ds0;
    ushort_t tmp[16];
    *(uint4*)&tmp[0] = *(const uint4*)&vsrc[0];
    *(uint4*)&tmp[8] = *(const uint4*)&vsrc[8];
#pragma unroll
    for (int i = 0; i < 16; ++i) Vt[ds0 + i][key] = tmp[i];
  }

  const int lane = tid & 63, w = tid >> 6;
  const int quad = lane >> 4, l16 = lane & 15;

  const ushort_t* qsrc = qb + (size_t)(b * 64 + w * 16 + l16) * DM + h * HD + quad * 8;
  bf16x8 aq0 = *(const bf16x8*)&qsrc[0];
  bf16x8 aq1 = *(const bf16x8*)&qsrc[32];

  // S = Q K^T
  f32x4 acc[4] = {};
#pragma unroll
  for (int nt = 0; nt < 4; ++nt) {
    const ushort_t* ksrc = kv + (size_t)(b * SEQ + c0 + nt * 16 + l16) * NKV + h * HD + quad * 8;
    bf16x8 bk0 = *(const bf16x8*)&ksrc[0];
    bf16x8 bk1 = *(const bf16x8*)&ksrc[32];
    acc[nt] = __builtin_amdgcn_mfma_f32_16x16x32_bf16(aq0, bk0, acc[nt], 0, 0, 0);
    acc[nt] = __builtin_amdgcn_mfma_f32_16x16x32_bf16(aq1, bk1, acc[nt], 0, 0, 0);
  }

  // per-chunk softmax
  float p[4][4];
  float mrow[4], lrow[4];
#pragma unroll
  for (int r = 0; r < 4; ++r) {
    const int q = w * 16 + quad * 4 + r;
    const int t = tS[q];
    float mx = -1e30f;
#pragma unroll
    for (int nt = 0; nt < 4; ++nt) {
      float s = acc[nt][r] * 0.125f;
      if (c0 + nt * 16 + l16 > t) s = -1e30f;
      p[nt][r] = s;
      mx = fmaxf(mx, s);
    }
#pragma unroll
    for (int off = 1; off < 16; off <<= 1) mx = fmaxf(mx, __shfl_xor(mx, off));
    float sum = 0.f;
#pragma unroll
    for (int nt = 0; nt < 4; ++nt) {
      float pv = __expf(p[nt][r] - mx);
      p[nt][r] = pv;
      sum += pv;
    }
#pragma unroll
    for (int off = 1; off < 16; off <<= 1) sum += __shfl_xor(sum, off);
    mrow[r] = mx; lrow[r] = sum;
  }

  const size_t pbase = ((size_t)(b * NH + h) * NCHUNK + c) * 64;
  if (l16 == 0) {
#pragma unroll
    for (int r = 0; r < 4; ++r) {
      const int q = w * 16 + quad * 4 + r;
      m_part[pbase + q] = mrow[r];
      l_part[pbase + q] = lrow[r];
    }
  }

  // P -> LDS (A-layout source)
#pragma unroll
  for (int r = 0; r < 4; ++r)
#pragma unroll
    for (int nt = 0; nt < 4; ++nt)
      Ps[w][quad * 4 + r][nt * 16 + l16] = f2bf(p[nt][r]);
  __syncthreads();

  // O = P V
  bf16x8 ap0 = *(const bf16x8*)&Ps[w][l16][quad * 8];
  bf16x8 ap1 = *(const bf16x8*)&Ps[w][l16][32 + quad * 8];
  f32x4 acc2[4] = {};
#pragma unroll
  for (int nt = 0; nt < 4; ++nt) {
    bf16x8 bv0 = *(const bf16x8*)&Vt[nt * 16 + l16][quad * 8];
    bf16x8 bv1 = *(const bf16x8*)&Vt[nt * 16 + l16][32 + quad * 8];
    acc2[nt] = __builtin_amdgcn_mfma_f32_16x16x32_bf16(ap0, bv0, acc2[nt], 0, 0, 0);
    acc2[nt] = __builtin_amdgcn_mfma_f32_16x16x32_bf16(ap1, bv1, acc2[nt], 0, 0, 0);
  }
  ushort_t* obp = o_part + pbase * 64;
#pragma unroll
  for (int nt = 0; nt < 4; ++nt)
#pragma unroll
    for (int r = 0; r < 4; ++r)
      obp[(w * 16 + quad * 4 + r) * 64 + nt * 16 + l16] = f2bf(acc2[nt][r]);
}

// ---------------------------------------------------------------------------
// combine partials -> ctx (bf16, padded [128][768]): grid (3, 12, 2)
// ---------------------------------------------------------------------------
__global__ __launch_bounds__(256) void attn_combine_kernel(
    const float* __restrict__ m_part, const float* __restrict__ l_part,
    const ushort_t* __restrict__ o_part, const int* __restrict__ idx,
    ushort_t* __restrict__ ctx_bf) {
  __shared__ float wgt[NCHUNK][16];
  __shared__ float linv[16];
  __shared__ int ncS[16];
  const int rg = blockIdx.x, h = blockIdx.y, b = blockIdx.z;
  const int tid = threadIdx.x;
  const size_t base = (size_t)(b * NH + h) * NCHUNK * 64;
  if (tid < 16) {
    const int q = rg * 16 + tid;
    float L = 0.f; int nc = 0;
    if (q < KSEL) {
      const int t = idx[b * KSEL + q];
      nc = (t >> 6) + 1;
      float M = -1e30f;
      for (int cc = 0; cc < nc; ++cc)
        M = fmaxf(M, m_part[base + cc * 64 + q]);
      for (int cc = 0; cc < nc; ++cc) {
        float wv = __expf(m_part[base + cc * 64 + q] - M);
        wgt[cc][tid] = wv;
        L += wv * l_part[base + cc * 64 + q];
      }
    }
    ncS[tid] = nc;
    linv[tid] = (L > 0.f) ? 1.0f / L : 0.f;
  }
  __syncthreads();
  const int rl = tid >> 4;
  const int d4 = (tid & 15) * 4;
  const int q = rg * 16 + rl;
  if (q >= KSEL) return;
  const int nc = ncS[rl];
  float4 a = {0.f, 0.f, 0.f, 0.f};
  const ushort_t* obp = o_part + base * 64 + (size_t)q * 64 + d4;
  for (int cc = 0; cc < nc; ++cc) {
    const float wv = wgt[cc][rl];
    const ushort4 ov = *(const ushort4*)&obp[(size_t)cc * 4096];
    a.x += wv * bf2f(ov.x); a.y += wv * bf2f(ov.y);
    a.z += wv * bf2f(ov.z); a.w += wv * bf2f(ov.w);
  }
  const float li = linv[rl];
  ushort4 o;
  o.x = f2bf(a.x * li); o.y = f2bf(a.y * li);
  o.z = f2bf(a.z * li); o.w = f2bf(a.w * li);
  *(ushort4*)&ctx_bf[(size_t)(b * 64 + q) * DM + h * HD + d4] = o;
}

// ---------------------------------------------------------------------------
// out-proj GEMM (bf16 MFMA, 24 blocks): gated = (ctx @ WoT^T + ob) * sel,
// scatter-added straight into y via atomicAdd.
// M=128 (92 valid), N-tile=64 (12 tiles), split-K=2 (384 each).
// Bias added only by the kb==0 block.
// ---------------------------------------------------------------------------
__global__ __launch_bounds__(256) void outproj_kernel(
    const ushort_t* __restrict__ ctx_bf,  // [128][768]
    const ushort_t* __restrict__ WoT,     // [768][768]
    const float* __restrict__ ob, const int* __restrict__ idx,
    const float* __restrict__ sel, float* __restrict__ y) {
  __shared__ ushort_t As[128 * 32];
  __shared__ ushort_t Bs[64 * 32];
  const int tid = threadIdx.x;
  const int lane = tid & 63, w = tid >> 6;
  const int wr = w >> 1, wc = w & 1;
  const int kb = blockIdx.x / 12;          // split-K half
  const int n0 = (blockIdx.x % 12) * 64;   // output-col tile
  const int kbase = kb * 384;
  const int quad = lane >> 4, l16 = lane & 15;
  const int ci0 = tid;
  const int ci1 = 256 + tid;
  const size_t ga0 = (size_t)(ci0 >> 2) * DM;
  const size_t ga1 = (size_t)(ci1 >> 2) * DM;
  const size_t gb0 = (size_t)(n0 + (tid >> 2)) * DM;  // 64 B rows
  const int ka0 = (ci0 & 3) * 8, ka1 = (ci1 & 3) * 8;
  const int kq = (tid & 3) * 8;
  f32x4 acc[4][2] = {};
  for (int k0 = kbase; k0 < kbase + 384; k0 += 32) {
    GLD16(ctx_bf + ga0 + k0 + ka0, &As[(w * 64) * 8]);
    GLD16(ctx_bf + ga1 + k0 + ka1, &As[(256 + w * 64) * 8]);
    GLD16(WoT + gb0 + k0 + kq, &Bs[(w * 16) * 32]);
    __syncthreads();
    bf16x8 af[4], bfr[2];
#pragma unroll
    for (int i = 0; i < 4; ++i)
      af[i] = *(const bf16x8*)&As[(wr * 64 + i * 16 + l16) * 32 + quad * 8];
#pragma unroll
    for (int j = 0; j < 2; ++j)
      bfr[j] = *(const bf16x8*)&Bs[(wc * 32 + j * 16 + l16) * 32 + quad * 8];
#pragma unroll
    for (int i = 0; i < 4; ++i)
#pragma unroll
      for (int j = 0; j < 2; ++j)
        acc[i][j] = __builtin_amdgcn_mfma_f32_16x16x32_bf16(af[i], bfr[j], acc[i][j], 0, 0, 0);
    __syncthreads();
  }
#pragma unroll
  for (int i = 0; i < 4; ++i) {
#pragma unroll
    for (int r = 0; r < 4; ++r) {
      const int row = wr * 64 + i * 16 + quad * 4 + r;
      const int b = row >> 6, jj = row & 63;
      if (jj >= KSEL) continue;
      const int t = idx[b * KSEL + jj];
      const float sv = sel[b * SEQ + t];
      float* yr = y + (size_t)(b * SEQ + t) * DM;
#pragma unroll
      for (int j = 0; j < 2; ++j) {
        const int col = n0 + wc * 32 + j * 16 + l16;
        const float bv = (kb == 0) ? ob[col] : 0.f;
        atomicAdd(&yr[col], (acc[i][j][r] + bv) * sv);
      }
    }
  }
}

// ---------------------------------------------------------------------------
extern "C" void kernel_launch(void* const* d_in, const int* in_sizes, int n_in,
                              void* d_out, int out_size, void* d_ws, size_t ws_size,
                              hipStream_t stream) {
  const float* x      = (const float*)d_in[0];
  const float* Wqkv_w = (const float*)d_in[1];
  const float* Wqkv_b = (const float*)d_in[2];
  const float* sel_w  = (const float*)d_in[3];
  const float* sel_b  = (const float*)d_in[4];
  const float* out_w  = (const float*)d_in[5];
  const float* out_b  = (const float*)d_in[6];
  const float* temp   = (const float*)d_in[7];
  float* y = (float*)d_out;

  // workspace layout (bytes, all 16B aligned)
  char* wsb = (char*)d_ws;
  ushort_t* kv     = (ushort_t*)wsb;  wsb += (size_t)BATCH * SEQ * NKV * 2;        // 12.58 MB
  ushort_t* o_part = (ushort_t*)wsb;  wsb += (size_t)24 * NCHUNK * 64 * 64 * 2;    // 6.29 MB
  float*    m_part = (float*)wsb;     wsb += (size_t)24 * NCHUNK * 64 * 4;
  float*    l_part = (float*)wsb;     wsb += (size_t)24 * NCHUNK * 64 * 4;
  float*    sel    = (float*)wsb;     wsb += (size_t)BATCH * SEQ * 4;
  int*      idx    = (int*)wsb;       wsb += 128 * 4;
  int*      idxp   = (int*)wsb;       wsb += 128 * 4;
  ushort_t* ctx_bf = (ushort_t*)wsb;  wsb += (size_t)128 * DM * 2;
  ushort_t* qb     = (ushort_t*)wsb;  wsb += (size_t)128 * DM * 2;
  ushort_t* Xbf    = (ushort_t*)wsb;  wsb += (size_t)BATCH * SEQ * DM * 2;         // 6.29 MB
  ushort_t* Wt     = (ushort_t*)wsb;  wsb += (size_t)N3 * DM * 2;                  // 3.54 MB
  ushort_t* WoT    = (ushort_t*)wsb;  wsb += (size_t)DM * DM * 2;                  // 1.18 MB

  prep_kernel<<<dim3(3328), 256, 0, stream>>>(x, Wqkv_w, out_w, sel_w, sel_b, temp,
                                              Xbf, Wt, WoT, sel, y);
  topk_kernel<<<dim3(BATCH), 256, 0, stream>>>(sel, idx, idxp);
  gemm_kernel<<<dim3(780), 256, 0, stream>>>(Xbf, Wt, Wqkv_b, idxp, kv, qb);
  attn_chunk_kernel<<<dim3(NCHUNK, NH, BATCH), 256, 0, stream>>>(kv, qb, idx, m_part, l_part, o_part);
  attn_combine_kernel<<<dim3(3, NH, BATCH), 256, 0, stream>>>(m_part, l_part, o_part, idx, ctx_bf);
  outproj_kernel<<<dim3(6 * 4), 256, 0, stream>>>(ctx_bf, WoT, out_b, idx, sel, y);
}

// Round 6
// 152.759 us; speedup vs baseline: 1.0711x; 1.0268x over previous
//
#include <hip/hip_runtime.h>
#include <hip/hip_bf16.h>
#include <cstddef>

// Problem constants
#define BATCH 2
#define SEQ   2048
#define DM    768
#define NH    12
#define HD    64
#define N3    2304      // 3*DM
#define NKV   1536      // 2*DM (K,V cols)
#define KSEL  46        // ceil(sqrt(2048))
#define NROW  (BATCH*KSEL)  // 92
#define NCHUNK 32       // 2048/64

typedef unsigned short ushort_t;
typedef __attribute__((ext_vector_type(8))) short bf16x8;
typedef __attribute__((ext_vector_type(4))) float f32x4;

__device__ __forceinline__ ushort_t f2bf(float f) {
  union { __hip_bfloat16 h; ushort_t u; } cv;
  cv.h = __float2bfloat16(f);
  return cv.u;
}
__device__ __forceinline__ float bf2f(ushort_t u) {
  union { unsigned int i; float f; } cv;
  cv.i = ((unsigned int)u) << 16;
  return cv.f;
}

#define GLD16(g, l)                                                         \
  __builtin_amdgcn_global_load_lds(                                         \
      (const __attribute__((address_space(1))) void*)(g),                   \
      (__attribute__((address_space(3))) void*)(l), 16, 0, 0)

// ---------------------------------------------------------------------------
// prep: fused single-pass row kernel (cast x + y=x copy + sel logits: x read
// ONCE, 1024 blocks) + full-Wqkv transpose (1728) + WoT (576).
// Total 3328 blocks.
// ---------------------------------------------------------------------------
__global__ __launch_bounds__(256) void prep_kernel(
    const float* __restrict__ x, const float* __restrict__ W,
    const float* __restrict__ Wo,
    const float* __restrict__ sel_w, const float* __restrict__ sel_b,
    const float* __restrict__ temp,
    ushort_t* __restrict__ xb, ushort_t* __restrict__ Wt,
    ushort_t* __restrict__ WoT,
    float* __restrict__ sel, float* __restrict__ y) {
  const int bx = blockIdx.x;
  const int tid = threadIdx.x;
  if (bx < 1024) {
    // one wave per row: read x once -> {y copy, bf16 cast, sel logits}
    const int w = tid >> 6, lane = tid & 63;
    const int row = bx * 4 + w;
    const float4* xr4 = (const float4*)(x + (size_t)row * DM);
    float4* yr4 = (float4*)(y + (size_t)row * DM);
    ushort4* xb4 = (ushort4*)(xb + (size_t)row * DM);
    const float4* sw4 = (const float4*)sel_w;
    float a0 = 0.f, a1 = 0.f;
#pragma unroll
    for (int i = 0; i < 3; ++i) {
      const int p = i * 64 + lane;          // float4 index within row
      float4 f = xr4[p];
      yr4[p] = f;
      ushort4 o;
      o.x = f2bf(f.x); o.y = f2bf(f.y); o.z = f2bf(f.z); o.w = f2bf(f.w);
      xb4[p] = o;
      // sel_w is [768][2] row-major; float4 pair covers k=4p..4p+3
      float4 sa = sw4[p * 2];
      float4 sb = sw4[p * 2 + 1];
      a0 += f.x * sa.x + f.y * sa.z + f.z * sb.x + f.w * sb.z;
      a1 += f.x * sa.y + f.y * sa.w + f.z * sb.y + f.w * sb.w;
    }
    for (int off = 32; off; off >>= 1) {
      a0 += __shfl_xor(a0, off);
      a1 += __shfl_xor(a1, off);
    }
    if (lane == 0) {
      float t = temp[0];
      float l0 = (a0 + sel_b[0]) / t;
      float l1 = (a1 + sel_b[1]) / t;
      sel[row] = 1.0f / (1.0f + expf(l0 - l1));
    }
  } else if (bx < 2752) {
    // Wt[n][k] = bf16(W[k][n]), all 2304 cols; 32x32 tiles
    __shared__ float tile[32][33];
    const int bx2 = bx - 1024;
    const int n0 = (bx2 % 72) * 32, k0 = (bx2 / 72) * 32;
    const int r = tid >> 3, c4 = (tid & 7) * 4;
    float4 f = *(const float4*)&W[(size_t)(k0 + r) * N3 + n0 + c4];
    tile[r][c4] = f.x; tile[r][c4 + 1] = f.y; tile[r][c4 + 2] = f.z; tile[r][c4 + 3] = f.w;
    __syncthreads();
    ushort4 o;
    o.x = f2bf(tile[c4 + 0][r]);
    o.y = f2bf(tile[c4 + 1][r]);
    o.z = f2bf(tile[c4 + 2][r]);
    o.w = f2bf(tile[c4 + 3][r]);
    *(ushort4*)&Wt[(size_t)(n0 + r) * DM + k0 + c4] = o;
  } else {
    // WoT[n][k] = bf16(Wo[k][n]); 32x32 tiles
    __shared__ float tile2[32][33];
    const int bx3 = bx - 2752;
    const int n0 = (bx3 % 24) * 32, k0 = (bx3 / 24) * 32;
    const int r = tid >> 3, c4 = (tid & 7) * 4;
    float4 f = *(const float4*)&Wo[(size_t)(k0 + r) * DM + n0 + c4];
    tile2[r][c4] = f.x; tile2[r][c4 + 1] = f.y; tile2[r][c4 + 2] = f.z; tile2[r][c4 + 3] = f.w;
    __syncthreads();
    ushort4 o;
    o.x = f2bf(tile2[c4 + 0][r]);
    o.y = f2bf(tile2[c4 + 1][r]);
    o.z = f2bf(tile2[c4 + 2][r]);
    o.w = f2bf(tile2[c4 + 3][r]);
    *(ushort4*)&WoT[(size_t)(n0 + r) * DM + k0 + c4] = o;
  }
}

// ---------------------------------------------------------------------------
// top-46 per batch via radix select on float bits (sel >= 0 -> monotone).
// grid 2 x 256.  Wave-shuffle suffix scan (5 barriers/pass).
// Emits the selected set in ASCENDING index order (deterministic; monotone
// gather locality downstream).  Ties keep lowest indices, matching
// jax.lax.top_k's selected SET.  Writes idx[b*46+j] and padded idxp[b*64+j].
// ---------------------------------------------------------------------------
__global__ __launch_bounds__(256) void topk_kernel(
    const float* __restrict__ sel, int* __restrict__ idx,
    int* __restrict__ idxp) {
  __shared__ unsigned int hist[256];
  __shared__ unsigned int cum[256];
  __shared__ unsigned int wtot[4];
  __shared__ int sh_b;
  __shared__ int c_gt, c_eq;
  __shared__ int tmp_gt[KSEL];
  __shared__ int eqlist[256];
  __shared__ int fin[64];
  __shared__ int srt[64];
  const int b = blockIdx.x, tid = threadIdx.x;
  const int lane = tid & 63, w = tid >> 6;

  unsigned int key[8];
  int  kidx[8];
#pragma unroll
  for (int e = 0; e < 8; ++e) {
    int i = e * 256 + tid;
    kidx[e] = i;
    key[e] = __float_as_uint(sel[b * SEQ + i]);
  }
  unsigned int prefix = 0, mask = 0;
  int r = KSEL;
#pragma unroll
  for (int p = 3; p >= 0; --p) {
    const int shift = 8 * p;
    hist[tid] = 0;
    __syncthreads();
#pragma unroll
    for (int e = 0; e < 8; ++e)
      if ((key[e] & mask) == prefix)
        atomicAdd(&hist[(key[e] >> shift) & 255], 1u);
    __syncthreads();
    unsigned int v = hist[tid];
#pragma unroll
    for (int off = 1; off < 64; off <<= 1) {
      unsigned int t = __shfl_down(v, off);
      if (lane + off < 64) v += t;
    }
    if (lane == 0) wtot[w] = v;
    __syncthreads();
    unsigned int addhi = 0;
    for (int ww = w + 1; ww < 4; ++ww) addhi += wtot[ww];
    v += addhi;
    cum[tid] = v;
    __syncthreads();
    if (v >= (unsigned int)r && (tid == 255 || cum[tid + 1] < (unsigned int)r))
      sh_b = tid;
    __syncthreads();
    const int bsel = sh_b;
    r -= (bsel == 255) ? 0 : (int)cum[bsel + 1];
    prefix |= ((unsigned int)bsel) << shift;
    mask |= 0xFFu << shift;
    __syncthreads();
  }
  // T = prefix; select all > T, plus r lowest-index == T
  if (tid == 0) { c_gt = 0; c_eq = 0; }
  __syncthreads();
#pragma unroll
  for (int e = 0; e < 8; ++e) {
    if (key[e] > prefix) {
      int pos = atomicAdd(&c_gt, 1);
      tmp_gt[pos] = kidx[e];
    } else if (key[e] == prefix) {
      int pos = atomicAdd(&c_eq, 1);
      if (pos < 256) eqlist[pos] = kidx[e];
    }
  }
  __syncthreads();
  if (tid == 0) {
    const int need = KSEL - c_gt;
    const int ec = (c_eq < 256) ? c_eq : 256;
    for (int a = 0; a < need; ++a) {       // selection of smallest indices
      int mb = a;
      for (int bb = a + 1; bb < ec; ++bb)
        if (eqlist[bb] < eqlist[mb]) mb = bb;
      int tv = eqlist[a]; eqlist[a] = eqlist[mb]; eqlist[mb] = tv;
    }
  }
  __syncthreads();
  if (tid < KSEL)
    fin[tid] = (tid < c_gt) ? tmp_gt[tid] : eqlist[tid - c_gt];
  __syncthreads();
  if (tid < KSEL) {
    const int v = fin[tid];
    int rank = 0;
    for (int j = 0; j < KSEL; ++j) rank += (fin[j] < v);
    srt[rank] = v;   // indices distinct -> ranks unique
  }
  __syncthreads();
  if (tid < 64) {
    if (tid < KSEL) {
      idx[b * KSEL + tid] = srt[tid];
      idxp[b * 64 + tid] = srt[tid];
    } else {
      idxp[b * 64 + tid] = 0;
    }
  }
}

// ---------------------------------------------------------------------------
// Fused GEMM (bf16 MFMA), 390 blocks, 128x128 tile, BK=64 (12 k-phases,
// 32 MFMA per barrier-pair -- halves barrier count vs BK=32):
//   blocks [0,384): kv[4096,1536] = Xbf @ Wt[768:2304]^T + bias  (bf16 out)
//     XCD-chunked swizzle (bid&7)*48 + bid>>3 (bijective: 384 % 8 == 0).
//   blocks [384,390): qb[128,768] = Xbf[gathered rows] @ Wt[0:768]^T + bias
// LDS: As/Bs [128][64] bf16 (128B rows).  Naive reads would 16-way bank
// conflict; per rule-21 we keep the global_load_lds DEST linear, permute the
// global SOURCE chunk (chunk' = chunk ^ (row&7)), and apply the same XOR on
// ds_read -> 2-way (free).  Accumulation visits k in the same order as BK=32
// -> bit-identical numerics.
// ---------------------------------------------------------------------------
__global__ __launch_bounds__(256) void gemm_kernel(
    const ushort_t* __restrict__ Xbf,   // [4096][768]
    const ushort_t* __restrict__ Wt,    // [2304][768]
    const float* __restrict__ bias,     // 2304
    const int* __restrict__ idxp,       // [128] padded selected rows
    ushort_t* __restrict__ Ckv,         // [4096][1536] bf16
    ushort_t* __restrict__ qb) {        // [128][768] bf16
  __shared__ ushort_t As[128 * 64];
  __shared__ ushort_t Bs[128 * 64];
  const int bid = blockIdx.x;
  const int tid = threadIdx.x;
  const int lane = tid & 63, w = tid >> 6;
  const int wr = w >> 1, wc = w & 1;
  const int quad = lane >> 4, l16 = lane & 15;
  const bool isQ = (bid >= 384);
  int m0, n0;
  // staging decomposition: call j=0..3, linear 16B-chunk = (j*4+w)*64 + lane;
  // row = chunk>>3 (0..127), cI = chunk&7, swizzled source chunk = cI^(row&7)
  int srow[4], scol[4];
#pragma unroll
  for (int j = 0; j < 4; ++j) {
    const int chunk = (j * 4 + w) * 64 + lane;
    srow[j] = chunk >> 3;
    scol[j] = ((chunk & 7) ^ (srow[j] & 7)) * 8;   // element offset in row
  }
  size_t gaRow[4], gbRow[4];
  if (isQ) {
    m0 = 0;
    n0 = (bid - 384) * 128;
#pragma unroll
    for (int j = 0; j < 4; ++j)
      gaRow[j] = (size_t)((srow[j] >> 6) * SEQ + idxp[srow[j]]) * DM;
  } else {
    const int bid2 = (bid & 7) * 48 + (bid >> 3);  // XCD-chunked swizzle
    m0 = (bid2 / 12) * 128;
    n0 = 768 + (bid2 % 12) * 128;
#pragma unroll
    for (int j = 0; j < 4; ++j)
      gaRow[j] = (size_t)(m0 + srow[j]) * DM;
  }
#pragma unroll
  for (int j = 0; j < 4; ++j)
    gbRow[j] = (size_t)(n0 + srow[j]) * DM;

  f32x4 acc[4][4] = {};
  for (int k0 = 0; k0 < DM; k0 += 64) {
#pragma unroll
    for (int j = 0; j < 4; ++j) {
      GLD16(Xbf + gaRow[j] + k0 + scol[j], &As[(j * 4 + w) * 512]);
      GLD16(Wt + gbRow[j] + k0 + scol[j], &Bs[(j * 4 + w) * 512]);
    }
    __syncthreads();
    bf16x8 af[4][2], bfr[4][2];
#pragma unroll
    for (int i = 0; i < 4; ++i) {
      const int row = wr * 64 + i * 16 + l16;
      const int sw = row & 7;
#pragma unroll
      for (int ks = 0; ks < 2; ++ks)
        af[i][ks] = *(const bf16x8*)&As[row * 64 + (((quad + ks * 4) ^ sw) * 8)];
    }
#pragma unroll
    for (int j2 = 0; j2 < 4; ++j2) {
      const int row = wc * 64 + j2 * 16 + l16;
      const int sw = row & 7;
#pragma unroll
      for (int ks = 0; ks < 2; ++ks)
        bfr[j2][ks] = *(const bf16x8*)&Bs[row * 64 + (((quad + ks * 4) ^ sw) * 8)];
    }
#pragma unroll
    for (int i = 0; i < 4; ++i)
#pragma unroll
      for (int j2 = 0; j2 < 4; ++j2) {
        acc[i][j2] = __builtin_amdgcn_mfma_f32_16x16x32_bf16(af[i][0], bfr[j2][0], acc[i][j2], 0, 0, 0);
        acc[i][j2] = __builtin_amdgcn_mfma_f32_16x16x32_bf16(af[i][1], bfr[j2][1], acc[i][j2], 0, 0, 0);
      }
    __syncthreads();
  }
#pragma unroll
  for (int i = 0; i < 4; ++i) {
    const int row_base = wr * 64 + i * 16 + quad * 4;
#pragma unroll
    for (int j = 0; j < 4; ++j) {
      const int col = n0 + wc * 64 + j * 16 + l16;
      const float bv = bias[col];
      if (isQ) {
#pragma unroll
        for (int r = 0; r < 4; ++r)
          qb[(size_t)(row_base + r) * DM + col] = f2bf(acc[i][j][r] + bv);
      } else {
#pragma unroll
        for (int r = 0; r < 4; ++r)
          Ckv[(size_t)(m0 + row_base + r) * NKV + (col - 768)] = f2bf(acc[i][j][r] + bv);
      }
    }
  }
}

// ---------------------------------------------------------------------------
// attention chunk kernel: grid (32 chunks, 12 h, 2 b), 256 thr = 4 waves.
// S[64x64] via MFMA, per-chunk softmax, PV via MFMA, bf16 partial O.
// ---------------------------------------------------------------------------
__global__ __launch_bounds__(256) void attn_chunk_kernel(
    const ushort_t* __restrict__ kv,   // [4096][1536] bf16
    const ushort_t* __restrict__ qb,   // [128][768] bf16
    const int* __restrict__ idx,
    float* __restrict__ m_part, float* __restrict__ l_part,
    ushort_t* __restrict__ o_part) {
  __shared__ __align__(16) ushort_t Vt[64][72];
  __shared__ __align__(16) ushort_t Ps[4][16][72];
  __shared__ int tS[64];
  __shared__ int tmaxS;
  const int tid = threadIdx.x;
  const int c = blockIdx.x, h = blockIdx.y, b = blockIdx.z;
  const int c0 = c * 64;
  if (tid < 64) {
    int t = (tid < KSEL) ? idx[b * KSEL + tid] : -1;
    tS[tid] = t;
    int tm = t;
    for (int off = 32; off; off >>= 1) tm = max(tm, __shfl_xor(tm, off));
    if (tid == 0) tmaxS = tm;
  }
  __syncthreads();
  if (c0 > tmaxS) return;   // uniform across block

  // stage V transposed: Vt[d][key]
  {
    const int key = tid >> 2, ds0 = (tid & 3) * 16;
    const ushort_t* vsrc = kv + (size_t)(b * SEQ + c0 + key) * NKV + DM + h * HD + ds0;
    ushort_t tmp[16];
    *(uint4*)&tmp[0] = *(const uint4*)&vsrc[0];
    *(uint4*)&tmp[8] = *(const uint4*)&vsrc[8];
#pragma unroll
    for (int i = 0; i < 16; ++i) Vt[ds0 + i][key] = tmp[i];
  }

  const int lane = tid & 63, w = tid >> 6;
  const int quad = lane >> 4, l16 = lane & 15;

  const ushort_t* qsrc = qb + (size_t)(b * 64 + w * 16 + l16) * DM + h * HD + quad * 8;
  bf16x8 aq0 = *(const bf16x8*)&qsrc[0];
  bf16x8 aq1 = *(const bf16x8*)&qsrc[32];

  // S = Q K^T
  f32x4 acc[4] = {};
#pragma unroll
  for (int nt = 0; nt < 4; ++nt) {
    const ushort_t* ksrc = kv + (size_t)(b * SEQ + c0 + nt * 16 + l16) * NKV + h * HD + quad * 8;
    bf16x8 bk0 = *(const bf16x8*)&ksrc[0];
    bf16x8 bk1 = *(const bf16x8*)&ksrc[32];
    acc[nt] = __builtin_amdgcn_mfma_f32_16x16x32_bf16(aq0, bk0, acc[nt], 0, 0, 0);
    acc[nt] = __builtin_amdgcn_mfma_f32_16x16x32_bf16(aq1, bk1, acc[nt], 0, 0, 0);
  }

  // per-chunk softmax
  float p[4][4];
  float mrow[4], lrow[4];
#pragma unroll
  for (int r = 0; r < 4; ++r) {
    const int q = w * 16 + quad * 4 + r;
    const int t = tS[q];
    float mx = -1e30f;
#pragma unroll
    for (int nt = 0; nt < 4; ++nt) {
      float s = acc[nt][r] * 0.125f;
      if (c0 + nt * 16 + l16 > t) s = -1e30f;
      p[nt][r] = s;
      mx = fmaxf(mx, s);
    }
#pragma unroll
    for (int off = 1; off < 16; off <<= 1) mx = fmaxf(mx, __shfl_xor(mx, off));
    float sum = 0.f;
#pragma unroll
    for (int nt = 0; nt < 4; ++nt) {
      float pv = __expf(p[nt][r] - mx);
      p[nt][r] = pv;
      sum += pv;
    }
#pragma unroll
    for (int off = 1; off < 16; off <<= 1) sum += __shfl_xor(sum, off);
    mrow[r] = mx; lrow[r] = sum;
  }

  const size_t pbase = ((size_t)(b * NH + h) * NCHUNK + c) * 64;
  if (l16 == 0) {
#pragma unroll
    for (int r = 0; r < 4; ++r) {
      const int q = w * 16 + quad * 4 + r;
      m_part[pbase + q] = mrow[r];
      l_part[pbase + q] = lrow[r];
    }
  }

  // P -> LDS (A-layout source)
#pragma unroll
  for (int r = 0; r < 4; ++r)
#pragma unroll
    for (int nt = 0; nt < 4; ++nt)
      Ps[w][quad * 4 + r][nt * 16 + l16] = f2bf(p[nt][r]);
  __syncthreads();

  // O = P V
  bf16x8 ap0 = *(const bf16x8*)&Ps[w][l16][quad * 8];
  bf16x8 ap1 = *(const bf16x8*)&Ps[w][l16][32 + quad * 8];
  f32x4 acc2[4] = {};
#pragma unroll
  for (int nt = 0; nt < 4; ++nt) {
    bf16x8 bv0 = *(const bf16x8*)&Vt[nt * 16 + l16][quad * 8];
    bf16x8 bv1 = *(const bf16x8*)&Vt[nt * 16 + l16][32 + quad * 8];
    acc2[nt] = __builtin_amdgcn_mfma_f32_16x16x32_bf16(ap0, bv0, acc2[nt], 0, 0, 0);
    acc2[nt] = __builtin_amdgcn_mfma_f32_16x16x32_bf16(ap1, bv1, acc2[nt], 0, 0, 0);
  }
  ushort_t* obp = o_part + pbase * 64;
#pragma unroll
  for (int nt = 0; nt < 4; ++nt)
#pragma unroll
    for (int r = 0; r < 4; ++r)
      obp[(w * 16 + quad * 4 + r) * 64 + nt * 16 + l16] = f2bf(acc2[nt][r]);
}

// ---------------------------------------------------------------------------
// combine partials -> ctx (bf16, padded [128][768]): grid (3, 12, 2)
// ---------------------------------------------------------------------------
__global__ __launch_bounds__(256) void attn_combine_kernel(
    const float* __restrict__ m_part, const float* __restrict__ l_part,
    const ushort_t* __restrict__ o_part, const int* __restrict__ idx,
    ushort_t* __restrict__ ctx_bf) {
  __shared__ float wgt[NCHUNK][16];
  __shared__ float linv[16];
  __shared__ int ncS[16];
  const int rg = blockIdx.x, h = blockIdx.y, b = blockIdx.z;
  const int tid = threadIdx.x;
  const size_t base = (size_t)(b * NH + h) * NCHUNK * 64;
  if (tid < 16) {
    const int q = rg * 16 + tid;
    float L = 0.f; int nc = 0;
    if (q < KSEL) {
      const int t = idx[b * KSEL + q];
      nc = (t >> 6) + 1;
      float M = -1e30f;
      for (int cc = 0; cc < nc; ++cc)
        M = fmaxf(M, m_part[base + cc * 64 + q]);
      for (int cc = 0; cc < nc; ++cc) {
        float wv = __expf(m_part[base + cc * 64 + q] - M);
        wgt[cc][tid] = wv;
        L += wv * l_part[base + cc * 64 + q];
      }
    }
    ncS[tid] = nc;
    linv[tid] = (L > 0.f) ? 1.0f / L : 0.f;
  }
  __syncthreads();
  const int rl = tid >> 4;
  const int d4 = (tid & 15) * 4;
  const int q = rg * 16 + rl;
  if (q >= KSEL) return;
  const int nc = ncS[rl];
  float4 a = {0.f, 0.f, 0.f, 0.f};
  const ushort_t* obp = o_part + base * 64 + (size_t)q * 64 + d4;
  for (int cc = 0; cc < nc; ++cc) {
    const float wv = wgt[cc][rl];
    const ushort4 ov = *(const ushort4*)&obp[(size_t)cc * 4096];
    a.x += wv * bf2f(ov.x); a.y += wv * bf2f(ov.y);
    a.z += wv * bf2f(ov.z); a.w += wv * bf2f(ov.w);
  }
  const float li = linv[rl];
  ushort4 o;
  o.x = f2bf(a.x * li); o.y = f2bf(a.y * li);
  o.z = f2bf(a.z * li); o.w = f2bf(a.w * li);
  *(ushort4*)&ctx_bf[(size_t)(b * 64 + q) * DM + h * HD + d4] = o;
}

// ---------------------------------------------------------------------------
// out-proj GEMM (bf16 MFMA, 24 blocks): gated = (ctx @ WoT^T + ob) * sel,
// scatter-added straight into y via atomicAdd.
// M=128 (92 valid), N-tile=64 (12 tiles), split-K=2 (384 each).
// Bias added only by the kb==0 block.
// ---------------------------------------------------------------------------
__global__ __launch_bounds__(256) void outproj_kernel(
    const ushort_t* __restrict__ ctx_bf,  // [128][768]
    const ushort_t* __restrict__ WoT,     // [768][768]
    const float* __restrict__ ob, const int* __restrict__ idx,
    const float* __restrict__ sel, float* __restrict__ y) {
  __shared__ ushort_t As[128 * 32];
  __shared__ ushort_t Bs[64 * 32];
  const int tid = threadIdx.x;
  const int lane = tid & 63, w = tid >> 6;
  const int wr = w >> 1, wc = w & 1;
  const int kb = blockIdx.x / 12;          // split-K half
  const int n0 = (blockIdx.x % 12) * 64;   // output-col tile
  const int kbase = kb * 384;
  const int quad = lane >> 4, l16 = lane & 15;
  const int ci0 = tid;
  const int ci1 = 256 + tid;
  const size_t ga0 = (size_t)(ci0 >> 2) * DM;
  const size_t ga1 = (size_t)(ci1 >> 2) * DM;
  const size_t gb0 = (size_t)(n0 + (tid >> 2)) * DM;  // 64 B rows
  const int ka0 = (ci0 & 3) * 8, ka1 = (ci1 & 3) * 8;
  const int kq = (tid & 3) * 8;
  f32x4 acc[4][2] = {};
  for (int k0 = kbase; k0 < kbase + 384; k0 += 32) {
    GLD16(ctx_bf + ga0 + k0 + ka0, &As[(w * 64) * 8]);
    GLD16(ctx_bf + ga1 + k0 + ka1, &As[(256 + w * 64) * 8]);
    GLD16(WoT + gb0 + k0 + kq, &Bs[(w * 16) * 32]);
    __syncthreads();
    bf16x8 af[4], bfr[2];
#pragma unroll
    for (int i = 0; i < 4; ++i)
      af[i] = *(const bf16x8*)&As[(wr * 64 + i * 16 + l16) * 32 + quad * 8];
#pragma unroll
    for (int j = 0; j < 2; ++j)
      bfr[j] = *(const bf16x8*)&Bs[(wc * 32 + j * 16 + l16) * 32 + quad * 8];
#pragma unroll
    for (int i = 0; i < 4; ++i)
#pragma unroll
      for (int j = 0; j < 2; ++j)
        acc[i][j] = __builtin_amdgcn_mfma_f32_16x16x32_bf16(af[i], bfr[j], acc[i][j], 0, 0, 0);
    __syncthreads();
  }
#pragma unroll
  for (int i = 0; i < 4; ++i) {
#pragma unroll
    for (int r = 0; r < 4; ++r) {
      const int row = wr * 64 + i * 16 + quad * 4 + r;
      const int b = row >> 6, jj = row & 63;
      if (jj >= KSEL) continue;
      const int t = idx[b * KSEL + jj];
      const float sv = sel[b * SEQ + t];
      float* yr = y + (size_t)(b * SEQ + t) * DM;
#pragma unroll
      for (int j = 0; j < 2; ++j) {
        const int col = n0 + wc * 32 + j * 16 + l16;
        const float bv = (kb == 0) ? ob[col] : 0.f;
        atomicAdd(&yr[col], (acc[i][j][r] + bv) * sv);
      }
    }
  }
}

// ---------------------------------------------------------------------------
extern "C" void kernel_launch(void* const* d_in, const int* in_sizes, int n_in,
                              void* d_out, int out_size, void* d_ws, size_t ws_size,
                              hipStream_t stream) {
  const float* x      = (const float*)d_in[0];
  const float* Wqkv_w = (const float*)d_in[1];
  const float* Wqkv_b = (const float*)d_in[2];
  const float* sel_w  = (const float*)d_in[3];
  const float* sel_b  = (const float*)d_in[4];
  const float* out_w  = (const float*)d_in[5];
  const float* out_b  = (const float*)d_in[6];
  const float* temp   = (const float*)d_in[7];
  float* y = (float*)d_out;

  // workspace layout (bytes, all 16B aligned)
  char* wsb = (char*)d_ws;
  ushort_t* kv     = (ushort_t*)wsb;  wsb += (size_t)BATCH * SEQ * NKV * 2;        // 12.58 MB
  ushort_t* o_part = (ushort_t*)wsb;  wsb += (size_t)24 * NCHUNK * 64 * 64 * 2;    // 6.29 MB
  float*    m_part = (float*)wsb;     wsb += (size_t)24 * NCHUNK * 64 * 4;
  float*    l_part = (float*)wsb;     wsb += (size_t)24 * NCHUNK * 64 * 4;
  float*    sel    = (float*)wsb;     wsb += (size_t)BATCH * SEQ * 4;
  int*      idx    = (int*)wsb;       wsb += 128 * 4;
  int*      idxp   = (int*)wsb;       wsb += 128 * 4;
  ushort_t* ctx_bf = (ushort_t*)wsb;  wsb += (size_t)128 * DM * 2;
  ushort_t* qb     = (ushort_t*)wsb;  wsb += (size_t)128 * DM * 2;
  ushort_t* Xbf    = (ushort_t*)wsb;  wsb += (size_t)BATCH * SEQ * DM * 2;         // 6.29 MB
  ushort_t* Wt     = (ushort_t*)wsb;  wsb += (size_t)N3 * DM * 2;                  // 3.54 MB
  ushort_t* WoT    = (ushort_t*)wsb;  wsb += (size_t)DM * DM * 2;                  // 1.18 MB

  prep_kernel<<<dim3(3328), 256, 0, stream>>>(x, Wqkv_w, out_w, sel_w, sel_b, temp,
                                              Xbf, Wt, WoT, sel, y);
  topk_kernel<<<dim3(BATCH), 256, 0, stream>>>(sel, idx, idxp);
  gemm_kernel<<<dim3(390), 256, 0, stream>>>(Xbf, Wt, Wqkv_b, idxp, kv, qb);
  attn_chunk_kernel<<<dim3(NCHUNK, NH, BATCH), 256, 0, stream>>>(kv, qb, idx, m_part, l_part, o_part);
  attn_combine_kernel<<<dim3(3, NH, BATCH), 256, 0, stream>>>(m_part, l_part, o_part, idx, ctx_bf);
  outproj_kernel<<<dim3(6 * 4), 256, 0, stream>>>(ctx_bf, WoT, out_b, idx, sel, y);
}

// Round 7
// 152.042 us; speedup vs baseline: 1.0762x; 1.0047x over previous
//
#include <hip/hip_runtime.h>
#include <hip/hip_bf16.h>
#include <cstddef>

// Problem constants
#define BATCH 2
#define SEQ   2048
#define DM    768
#define NH    12
#define HD    64
#define N3    2304      // 3*DM
#define NKV   1536      // 2*DM (K,V cols)
#define KSEL  46        // ceil(sqrt(2048))
#define NROW  (BATCH*KSEL)  // 92
#define NCHUNK 32       // 2048/64

typedef unsigned short ushort_t;
typedef __attribute__((ext_vector_type(8))) short bf16x8;
typedef __attribute__((ext_vector_type(4))) float f32x4;

__device__ __forceinline__ ushort_t f2bf(float f) {
  union { __hip_bfloat16 h; ushort_t u; } cv;
  cv.h = __float2bfloat16(f);
  return cv.u;
}
__device__ __forceinline__ float bf2f(ushort_t u) {
  union { unsigned int i; float f; } cv;
  cv.i = ((unsigned int)u) << 16;
  return cv.f;
}

#define GLD16(g, l)                                                         \
  __builtin_amdgcn_global_load_lds(                                         \
      (const __attribute__((address_space(1))) void*)(g),                   \
      (__attribute__((address_space(3))) void*)(l), 16, 0, 0)

// ---------------------------------------------------------------------------
// prep: fused single-pass row kernel (cast x + y=x copy + sel logits: x read
// ONCE, 1024 blocks) + full-Wqkv transpose (1728) + WoT (576).
// Total 3328 blocks.
// ---------------------------------------------------------------------------
__global__ __launch_bounds__(256) void prep_kernel(
    const float* __restrict__ x, const float* __restrict__ W,
    const float* __restrict__ Wo,
    const float* __restrict__ sel_w, const float* __restrict__ sel_b,
    const float* __restrict__ temp,
    ushort_t* __restrict__ xb, ushort_t* __restrict__ Wt,
    ushort_t* __restrict__ WoT,
    float* __restrict__ sel, float* __restrict__ y) {
  const int bx = blockIdx.x;
  const int tid = threadIdx.x;
  if (bx < 1024) {
    // one wave per row: read x once -> {y copy, bf16 cast, sel logits}
    const int w = tid >> 6, lane = tid & 63;
    const int row = bx * 4 + w;
    const float4* xr4 = (const float4*)(x + (size_t)row * DM);
    float4* yr4 = (float4*)(y + (size_t)row * DM);
    ushort4* xb4 = (ushort4*)(xb + (size_t)row * DM);
    const float4* sw4 = (const float4*)sel_w;
    float a0 = 0.f, a1 = 0.f;
#pragma unroll
    for (int i = 0; i < 3; ++i) {
      const int p = i * 64 + lane;          // float4 index within row
      float4 f = xr4[p];
      yr4[p] = f;
      ushort4 o;
      o.x = f2bf(f.x); o.y = f2bf(f.y); o.z = f2bf(f.z); o.w = f2bf(f.w);
      xb4[p] = o;
      // sel_w is [768][2] row-major; float4 pair covers k=4p..4p+3
      float4 sa = sw4[p * 2];
      float4 sb = sw4[p * 2 + 1];
      a0 += f.x * sa.x + f.y * sa.z + f.z * sb.x + f.w * sb.z;
      a1 += f.x * sa.y + f.y * sa.w + f.z * sb.y + f.w * sb.w;
    }
    for (int off = 32; off; off >>= 1) {
      a0 += __shfl_xor(a0, off);
      a1 += __shfl_xor(a1, off);
    }
    if (lane == 0) {
      float t = temp[0];
      float l0 = (a0 + sel_b[0]) / t;
      float l1 = (a1 + sel_b[1]) / t;
      sel[row] = 1.0f / (1.0f + expf(l0 - l1));
    }
  } else if (bx < 2752) {
    // Wt[n][k] = bf16(W[k][n]), all 2304 cols; 32x32 tiles
    __shared__ float tile[32][33];
    const int bx2 = bx - 1024;
    const int n0 = (bx2 % 72) * 32, k0 = (bx2 / 72) * 32;
    const int r = tid >> 3, c4 = (tid & 7) * 4;
    float4 f = *(const float4*)&W[(size_t)(k0 + r) * N3 + n0 + c4];
    tile[r][c4] = f.x; tile[r][c4 + 1] = f.y; tile[r][c4 + 2] = f.z; tile[r][c4 + 3] = f.w;
    __syncthreads();
    ushort4 o;
    o.x = f2bf(tile[c4 + 0][r]);
    o.y = f2bf(tile[c4 + 1][r]);
    o.z = f2bf(tile[c4 + 2][r]);
    o.w = f2bf(tile[c4 + 3][r]);
    *(ushort4*)&Wt[(size_t)(n0 + r) * DM + k0 + c4] = o;
  } else {
    // WoT[n][k] = bf16(Wo[k][n]); 32x32 tiles
    __shared__ float tile2[32][33];
    const int bx3 = bx - 2752;
    const int n0 = (bx3 % 24) * 32, k0 = (bx3 / 24) * 32;
    const int r = tid >> 3, c4 = (tid & 7) * 4;
    float4 f = *(const float4*)&Wo[(size_t)(k0 + r) * DM + n0 + c4];
    tile2[r][c4] = f.x; tile2[r][c4 + 1] = f.y; tile2[r][c4 + 2] = f.z; tile2[r][c4 + 3] = f.w;
    __syncthreads();
    ushort4 o;
    o.x = f2bf(tile2[c4 + 0][r]);
    o.y = f2bf(tile2[c4 + 1][r]);
    o.z = f2bf(tile2[c4 + 2][r]);
    o.w = f2bf(tile2[c4 + 3][r]);
    *(ushort4*)&WoT[(size_t)(n0 + r) * DM + k0 + c4] = o;
  }
}

// ---------------------------------------------------------------------------
// top-46 per batch via radix select on float bits (sel >= 0 -> monotone).
// grid 2 x 256.  Wave-shuffle suffix scan (5 barriers/pass).
// Emits the selected set in ASCENDING index order (deterministic; monotone
// gather locality downstream).  Ties keep lowest indices, matching
// jax.lax.top_k's selected SET.  Writes idx[b*46+j] and padded idxp[b*64+j].
// ---------------------------------------------------------------------------
__global__ __launch_bounds__(256) void topk_kernel(
    const float* __restrict__ sel, int* __restrict__ idx,
    int* __restrict__ idxp) {
  __shared__ unsigned int hist[256];
  __shared__ unsigned int cum[256];
  __shared__ unsigned int wtot[4];
  __shared__ int sh_b;
  __shared__ int c_gt, c_eq;
  __shared__ int tmp_gt[KSEL];
  __shared__ int eqlist[256];
  __shared__ int fin[64];
  __shared__ int srt[64];
  const int b = blockIdx.x, tid = threadIdx.x;
  const int lane = tid & 63, w = tid >> 6;

  unsigned int key[8];
  int  kidx[8];
#pragma unroll
  for (int e = 0; e < 8; ++e) {
    int i = e * 256 + tid;
    kidx[e] = i;
    key[e] = __float_as_uint(sel[b * SEQ + i]);
  }
  unsigned int prefix = 0, mask = 0;
  int r = KSEL;
#pragma unroll
  for (int p = 3; p >= 0; --p) {
    const int shift = 8 * p;
    hist[tid] = 0;
    __syncthreads();
#pragma unroll
    for (int e = 0; e < 8; ++e)
      if ((key[e] & mask) == prefix)
        atomicAdd(&hist[(key[e] >> shift) & 255], 1u);
    __syncthreads();
    unsigned int v = hist[tid];
#pragma unroll
    for (int off = 1; off < 64; off <<= 1) {
      unsigned int t = __shfl_down(v, off);
      if (lane + off < 64) v += t;
    }
    if (lane == 0) wtot[w] = v;
    __syncthreads();
    unsigned int addhi = 0;
    for (int ww = w + 1; ww < 4; ++ww) addhi += wtot[ww];
    v += addhi;
    cum[tid] = v;
    __syncthreads();
    if (v >= (unsigned int)r && (tid == 255 || cum[tid + 1] < (unsigned int)r))
      sh_b = tid;
    __syncthreads();
    const int bsel = sh_b;
    r -= (bsel == 255) ? 0 : (int)cum[bsel + 1];
    prefix |= ((unsigned int)bsel) << shift;
    mask |= 0xFFu << shift;
    __syncthreads();
  }
  // T = prefix; select all > T, plus r lowest-index == T
  if (tid == 0) { c_gt = 0; c_eq = 0; }
  __syncthreads();
#pragma unroll
  for (int e = 0; e < 8; ++e) {
    if (key[e] > prefix) {
      int pos = atomicAdd(&c_gt, 1);
      tmp_gt[pos] = kidx[e];
    } else if (key[e] == prefix) {
      int pos = atomicAdd(&c_eq, 1);
      if (pos < 256) eqlist[pos] = kidx[e];
    }
  }
  __syncthreads();
  if (tid == 0) {
    const int need = KSEL - c_gt;
    const int ec = (c_eq < 256) ? c_eq : 256;
    for (int a = 0; a < need; ++a) {       // selection of smallest indices
      int mb = a;
      for (int bb = a + 1; bb < ec; ++bb)
        if (eqlist[bb] < eqlist[mb]) mb = bb;
      int tv = eqlist[a]; eqlist[a] = eqlist[mb]; eqlist[mb] = tv;
    }
  }
  __syncthreads();
  if (tid < KSEL)
    fin[tid] = (tid < c_gt) ? tmp_gt[tid] : eqlist[tid - c_gt];
  __syncthreads();
  if (tid < KSEL) {
    const int v = fin[tid];
    int rank = 0;
    for (int j = 0; j < KSEL; ++j) rank += (fin[j] < v);
    srt[rank] = v;   // indices distinct -> ranks unique
  }
  __syncthreads();
  if (tid < 64) {
    if (tid < KSEL) {
      idx[b * KSEL + tid] = srt[tid];
      idxp[b * 64 + tid] = srt[tid];
    } else {
      idxp[b * 64 + tid] = 0;
    }
  }
}

// ---------------------------------------------------------------------------
// Fused GEMM (bf16 MFMA), 390 blocks, 128x128 tile, BK=64 (12 k-phases,
// 32 MFMA per barrier-pair -- halves barrier count vs BK=32):
//   blocks [0,384): kv[4096,1536] = Xbf @ Wt[768:2304]^T + bias  (bf16 out)
//     XCD-chunked swizzle (bid&7)*48 + bid>>3 (bijective: 384 % 8 == 0).
//   blocks [384,390): qb[128,768] = Xbf[gathered rows] @ Wt[0:768]^T + bias
// LDS: As/Bs [128][64] bf16 (128B rows).  Naive reads would 16-way bank
// conflict; per rule-21 we keep the global_load_lds DEST linear, permute the
// global SOURCE chunk (chunk' = chunk ^ (row&7)), and apply the same XOR on
// ds_read -> 2-way (free).  Accumulation visits k in the same order as BK=32
// -> bit-identical numerics.
// ---------------------------------------------------------------------------
__global__ __launch_bounds__(256) void gemm_kernel(
    const ushort_t* __restrict__ Xbf,   // [4096][768]
    const ushort_t* __restrict__ Wt,    // [2304][768]
    const float* __restrict__ bias,     // 2304
    const int* __restrict__ idxp,       // [128] padded selected rows
    ushort_t* __restrict__ Ckv,         // [4096][1536] bf16
    ushort_t* __restrict__ qb) {        // [128][768] bf16
  __shared__ ushort_t As[128 * 64];
  __shared__ ushort_t Bs[128 * 64];
  const int bid = blockIdx.x;
  const int tid = threadIdx.x;
  const int lane = tid & 63, w = tid >> 6;
  const int wr = w >> 1, wc = w & 1;
  const int quad = lane >> 4, l16 = lane & 15;
  const bool isQ = (bid >= 384);
  int m0, n0;
  // staging decomposition: call j=0..3, linear 16B-chunk = (j*4+w)*64 + lane;
  // row = chunk>>3 (0..127), cI = chunk&7, swizzled source chunk = cI^(row&7)
  int srow[4], scol[4];
#pragma unroll
  for (int j = 0; j < 4; ++j) {
    const int chunk = (j * 4 + w) * 64 + lane;
    srow[j] = chunk >> 3;
    scol[j] = ((chunk & 7) ^ (srow[j] & 7)) * 8;   // element offset in row
  }
  size_t gaRow[4], gbRow[4];
  if (isQ) {
    m0 = 0;
    n0 = (bid - 384) * 128;
#pragma unroll
    for (int j = 0; j < 4; ++j)
      gaRow[j] = (size_t)((srow[j] >> 6) * SEQ + idxp[srow[j]]) * DM;
  } else {
    const int bid2 = (bid & 7) * 48 + (bid >> 3);  // XCD-chunked swizzle
    m0 = (bid2 / 12) * 128;
    n0 = 768 + (bid2 % 12) * 128;
#pragma unroll
    for (int j = 0; j < 4; ++j)
      gaRow[j] = (size_t)(m0 + srow[j]) * DM;
  }
#pragma unroll
  for (int j = 0; j < 4; ++j)
    gbRow[j] = (size_t)(n0 + srow[j]) * DM;

  f32x4 acc[4][4] = {};
  for (int k0 = 0; k0 < DM; k0 += 64) {
#pragma unroll
    for (int j = 0; j < 4; ++j) {
      GLD16(Xbf + gaRow[j] + k0 + scol[j], &As[(j * 4 + w) * 512]);
      GLD16(Wt + gbRow[j] + k0 + scol[j], &Bs[(j * 4 + w) * 512]);
    }
    __syncthreads();
    bf16x8 af[4][2], bfr[4][2];
#pragma unroll
    for (int i = 0; i < 4; ++i) {
      const int row = wr * 64 + i * 16 + l16;
      const int sw = row & 7;
#pragma unroll
      for (int ks = 0; ks < 2; ++ks)
        af[i][ks] = *(const bf16x8*)&As[row * 64 + (((quad + ks * 4) ^ sw) * 8)];
    }
#pragma unroll
    for (int j2 = 0; j2 < 4; ++j2) {
      const int row = wc * 64 + j2 * 16 + l16;
      const int sw = row & 7;
#pragma unroll
      for (int ks = 0; ks < 2; ++ks)
        bfr[j2][ks] = *(const bf16x8*)&Bs[row * 64 + (((quad + ks * 4) ^ sw) * 8)];
    }
#pragma unroll
    for (int i = 0; i < 4; ++i)
#pragma unroll
      for (int j2 = 0; j2 < 4; ++j2) {
        acc[i][j2] = __builtin_amdgcn_mfma_f32_16x16x32_bf16(af[i][0], bfr[j2][0], acc[i][j2], 0, 0, 0);
        acc[i][j2] = __builtin_amdgcn_mfma_f32_16x16x32_bf16(af[i][1], bfr[j2][1], acc[i][j2], 0, 0, 0);
      }
    __syncthreads();
  }
#pragma unroll
  for (int i = 0; i < 4; ++i) {
    const int row_base = wr * 64 + i * 16 + quad * 4;
#pragma unroll
    for (int j = 0; j < 4; ++j) {
      const int col = n0 + wc * 64 + j * 16 + l16;
      const float bv = bias[col];
      if (isQ) {
#pragma unroll
        for (int r = 0; r < 4; ++r)
          qb[(size_t)(row_base + r) * DM + col] = f2bf(acc[i][j][r] + bv);
      } else {
#pragma unroll
        for (int r = 0; r < 4; ++r)
          Ckv[(size_t)(m0 + row_base + r) * NKV + (col - 768)] = f2bf(acc[i][j][r] + bv);
      }
    }
  }
}

// ---------------------------------------------------------------------------
// attention chunk kernel: grid (32 chunks, 12 h, 2 b), 256 thr = 4 waves.
// S[64x64] via MFMA, per-chunk softmax, PV via MFMA, bf16 partial O.
// ---------------------------------------------------------------------------
__global__ __launch_bounds__(256) void attn_chunk_kernel(
    const ushort_t* __restrict__ kv,   // [4096][1536] bf16
    const ushort_t* __restrict__ qb,   // [128][768] bf16
    const int* __restrict__ idx,
    float* __restrict__ m_part, float* __restrict__ l_part,
    ushort_t* __restrict__ o_part) {
  __shared__ __align__(16) ushort_t Vt[64][72];
  __shared__ __align__(16) ushort_t Ps[4][16][72];
  __shared__ int tS[64];
  __shared__ int tmaxS;
  const int tid = threadIdx.x;
  const int c = blockIdx.x, h = blockIdx.y, b = blockIdx.z;
  const int c0 = c * 64;
  if (tid < 64) {
    int t = (tid < KSEL) ? idx[b * KSEL + tid] : -1;
    tS[tid] = t;
    int tm = t;
    for (int off = 32; off; off >>= 1) tm = max(tm, __shfl_xor(tm, off));
    if (tid == 0) tmaxS = tm;
  }
  __syncthreads();
  if (c0 > tmaxS) return;   // uniform across block

  // stage V transposed: Vt[d][key]
  {
    const int key = tid >> 2, ds0 = (tid & 3) * 16;
    const ushort_t* vsrc = kv + (size_t)(b * SEQ + c0 + key) * NKV + DM + h * HD + ds0;
    ushort_t tmp[16];
    *(uint4*)&tmp[0] = *(const uint4*)&vsrc[0];
    *(uint4*)&tmp[8] = *(const uint4*)&vsrc[8];
#pragma unroll
    for (int i = 0; i < 16; ++i) Vt[ds0 + i][key] = tmp[i];
  }

  const int lane = tid & 63, w = tid >> 6;
  const int quad = lane >> 4, l16 = lane & 15;

  const ushort_t* qsrc = qb + (size_t)(b * 64 + w * 16 + l16) * DM + h * HD + quad * 8;
  bf16x8 aq0 = *(const bf16x8*)&qsrc[0];
  bf16x8 aq1 = *(const bf16x8*)&qsrc[32];

  // S = Q K^T
  f32x4 acc[4] = {};
#pragma unroll
  for (int nt = 0; nt < 4; ++nt) {
    const ushort_t* ksrc = kv + (size_t)(b * SEQ + c0 + nt * 16 + l16) * NKV + h * HD + quad * 8;
    bf16x8 bk0 = *(const bf16x8*)&ksrc[0];
    bf16x8 bk1 = *(const bf16x8*)&ksrc[32];
    acc[nt] = __builtin_amdgcn_mfma_f32_16x16x32_bf16(aq0, bk0, acc[nt], 0, 0, 0);
    acc[nt] = __builtin_amdgcn_mfma_f32_16x16x32_bf16(aq1, bk1, acc[nt], 0, 0, 0);
  }

  // per-chunk softmax
  float p[4][4];
  float mrow[4], lrow[4];
#pragma unroll
  for (int r = 0; r < 4; ++r) {
    const int q = w * 16 + quad * 4 + r;
    const int t = tS[q];
    float mx = -1e30f;
#pragma unroll
    for (int nt = 0; nt < 4; ++nt) {
      float s = acc[nt][r] * 0.125f;
      if (c0 + nt * 16 + l16 > t) s = -1e30f;
      p[nt][r] = s;
      mx = fmaxf(mx, s);
    }
#pragma unroll
    for (int off = 1; off < 16; off <<= 1) mx = fmaxf(mx, __shfl_xor(mx, off));
    float sum = 0.f;
#pragma unroll
    for (int nt = 0; nt < 4; ++nt) {
      float pv = __expf(p[nt][r] - mx);
      p[nt][r] = pv;
      sum += pv;
    }
#pragma unroll
    for (int off = 1; off < 16; off <<= 1) sum += __shfl_xor(sum, off);
    mrow[r] = mx; lrow[r] = sum;
  }

  const size_t pbase = ((size_t)(b * NH + h) * NCHUNK + c) * 64;
  if (l16 == 0) {
#pragma unroll
    for (int r = 0; r < 4; ++r) {
      const int q = w * 16 + quad * 4 + r;
      m_part[pbase + q] = mrow[r];
      l_part[pbase + q] = lrow[r];
    }
  }

  // P -> LDS (A-layout source)
#pragma unroll
  for (int r = 0; r < 4; ++r)
#pragma unroll
    for (int nt = 0; nt < 4; ++nt)
      Ps[w][quad * 4 + r][nt * 16 + l16] = f2bf(p[nt][r]);
  __syncthreads();

  // O = P V
  bf16x8 ap0 = *(const bf16x8*)&Ps[w][l16][quad * 8];
  bf16x8 ap1 = *(const bf16x8*)&Ps[w][l16][32 + quad * 8];
  f32x4 acc2[4] = {};
#pragma unroll
  for (int nt = 0; nt < 4; ++nt) {
    bf16x8 bv0 = *(const bf16x8*)&Vt[nt * 16 + l16][quad * 8];
    bf16x8 bv1 = *(const bf16x8*)&Vt[nt * 16 + l16][32 + quad * 8];
    acc2[nt] = __builtin_amdgcn_mfma_f32_16x16x32_bf16(ap0, bv0, acc2[nt], 0, 0, 0);
    acc2[nt] = __builtin_amdgcn_mfma_f32_16x16x32_bf16(ap1, bv1, acc2[nt], 0, 0, 0);
  }
  ushort_t* obp = o_part + pbase * 64;
#pragma unroll
  for (int nt = 0; nt < 4; ++nt)
#pragma unroll
    for (int r = 0; r < 4; ++r)
      obp[(w * 16 + quad * 4 + r) * 64 + nt * 16 + l16] = f2bf(acc2[nt][r]);
}

// ---------------------------------------------------------------------------
// combine partials -> ctx (bf16, padded [128][768]): grid (3, 12, 2)
// ---------------------------------------------------------------------------
__global__ __launch_bounds__(256) void attn_combine_kernel(
    const float* __restrict__ m_part, const float* __restrict__ l_part,
    const ushort_t* __restrict__ o_part, const int* __restrict__ idx,
    ushort_t* __restrict__ ctx_bf) {
  __shared__ float wgt[NCHUNK][16];
  __shared__ float linv[16];
  __shared__ int ncS[16];
  const int rg = blockIdx.x, h = blockIdx.y, b = blockIdx.z;
  const int tid = threadIdx.x;
  const size_t base = (size_t)(b * NH + h) * NCHUNK * 64;
  if (tid < 16) {
    const int q = rg * 16 + tid;
    float L = 0.f; int nc = 0;
    if (q < KSEL) {
      const int t = idx[b * KSEL + q];
      nc = (t >> 6) + 1;
      float M = -1e30f;
      for (int cc = 0; cc < nc; ++cc)
        M = fmaxf(M, m_part[base + cc * 64 + q]);
      for (int cc = 0; cc < nc; ++cc) {
        float wv = __expf(m_part[base + cc * 64 + q] - M);
        wgt[cc][tid] = wv;
        L += wv * l_part[base + cc * 64 + q];
      }
    }
    ncS[tid] = nc;
    linv[tid] = (L > 0.f) ? 1.0f / L : 0.f;
  }
  __syncthreads();
  const int rl = tid >> 4;
  const int d4 = (tid & 15) * 4;
  const int q = rg * 16 + rl;
  if (q >= KSEL) return;
  const int nc = ncS[rl];
  float4 a = {0.f, 0.f, 0.f, 0.f};
  const ushort_t* obp = o_part + base * 64 + (size_t)q * 64 + d4;
  for (int cc = 0; cc < nc; ++cc) {
    const float wv = wgt[cc][rl];
    const ushort4 ov = *(const ushort4*)&obp[(size_t)cc * 4096];
    a.x += wv * bf2f(ov.x); a.y += wv * bf2f(ov.y);
    a.z += wv * bf2f(ov.z); a.w += wv * bf2f(ov.w);
  }
  const float li = linv[rl];
  ushort4 o;
  o.x = f2bf(a.x * li); o.y = f2bf(a.y * li);
  o.z = f2bf(a.z * li); o.w = f2bf(a.w * li);
  *(ushort4*)&ctx_bf[(size_t)(b * 64 + q) * DM + h * HD + d4] = o;
}

// ---------------------------------------------------------------------------
// out-proj GEMM (bf16 MFMA, 24 blocks): gated = (ctx @ WoT^T + ob) * sel,
// scatter-added straight into y via atomicAdd.
// M=128 (92 valid), N-tile=64 (12 tiles), split-K=2 (384 each), BK=128 ->
// only 3 k-phases / 6 barriers (24 blocks = 1/CU, so barrier stalls are
// fully exposed; fewer barriers is the lever).
// LDS rows are 256B (row stride = 0 mod 32 banks); rule-21 involution on the
// low-3 chunk bits (ci' = (ci&8)|((ci&7)^(row&7))) gives 2-way (free) reads.
// k visited in same ascending order as BK=32 -> bit-identical numerics.
// Bias added only by the kb==0 block.
// ---------------------------------------------------------------------------
__global__ __launch_bounds__(256) void outproj_kernel(
    const ushort_t* __restrict__ ctx_bf,  // [128][768]
    const ushort_t* __restrict__ WoT,     // [768][768]
    const float* __restrict__ ob, const int* __restrict__ idx,
    const float* __restrict__ sel, float* __restrict__ y) {
  __shared__ ushort_t As[128 * 128];   // 32 KB
  __shared__ ushort_t Bs[64 * 128];    // 16 KB
  const int tid = threadIdx.x;
  const int lane = tid & 63, w = tid >> 6;
  const int wr = w >> 1, wc = w & 1;
  const int kb = blockIdx.x / 12;          // split-K half
  const int n0 = (blockIdx.x % 12) * 64;   // output-col tile
  const int kbase = kb * 384;
  const int quad = lane >> 4, l16 = lane & 15;
  // staging: As = 2048 chunks (8/thread), Bs = 1024 chunks (4/thread);
  // 16 chunks per 128-col row; swizzled source chunk-in-row:
  //   ci' = (ci&8) | ((ci&7) ^ (row&7))
  int srA[8], scA[8], srB[4], scB[4];
#pragma unroll
  for (int j = 0; j < 8; ++j) {
    const int chunk = (j * 4 + w) * 64 + lane;   // 0..2047
    srA[j] = chunk >> 4;                          // row 0..127
    const int ci = chunk & 15;
    scA[j] = ((ci & 8) | ((ci & 7) ^ (srA[j] & 7))) * 8;
  }
#pragma unroll
  for (int j = 0; j < 4; ++j) {
    const int chunk = (j * 4 + w) * 64 + lane;   // 0..1023
    srB[j] = chunk >> 4;                          // row 0..63
    const int ci = chunk & 15;
    scB[j] = ((ci & 8) | ((ci & 7) ^ (srB[j] & 7))) * 8;
  }
  f32x4 acc[4][2] = {};
  for (int k0 = kbase; k0 < kbase + 384; k0 += 128) {
#pragma unroll
    for (int j = 0; j < 8; ++j)
      GLD16(ctx_bf + (size_t)srA[j] * DM + k0 + scA[j], &As[(j * 4 + w) * 512]);
#pragma unroll
    for (int j = 0; j < 4; ++j)
      GLD16(WoT + (size_t)(n0 + srB[j]) * DM + k0 + scB[j], &Bs[(j * 4 + w) * 512]);
    __syncthreads();
    bf16x8 af[4][4], bfr[2][4];
#pragma unroll
    for (int i = 0; i < 4; ++i) {
      const int row = wr * 64 + i * 16 + l16;
      const int sw = row & 7;
#pragma unroll
      for (int ks = 0; ks < 4; ++ks) {
        const int ci = quad + ks * 4;            // logical chunk 0..15
        af[i][ks] = *(const bf16x8*)&As[row * 128 + (((ci & 8) | ((ci & 7) ^ sw)) * 8)];
      }
    }
#pragma unroll
    for (int j = 0; j < 2; ++j) {
      const int row = wc * 32 + j * 16 + l16;
      const int sw = row & 7;
#pragma unroll
      for (int ks = 0; ks < 4; ++ks) {
        const int ci = quad + ks * 4;
        bfr[j][ks] = *(const bf16x8*)&Bs[row * 128 + (((ci & 8) | ((ci & 7) ^ sw)) * 8)];
      }
    }
#pragma unroll
    for (int i = 0; i < 4; ++i)
#pragma unroll
      for (int j = 0; j < 2; ++j)
#pragma unroll
        for (int ks = 0; ks < 4; ++ks)
          acc[i][j] = __builtin_amdgcn_mfma_f32_16x16x32_bf16(af[i][ks], bfr[j][ks], acc[i][j], 0, 0, 0);
    __syncthreads();
  }
#pragma unroll
  for (int i = 0; i < 4; ++i) {
#pragma unroll
    for (int r = 0; r < 4; ++r) {
      const int row = wr * 64 + i * 16 + quad * 4 + r;
      const int b = row >> 6, jj = row & 63;
      if (jj >= KSEL) continue;
      const int t = idx[b * KSEL + jj];
      const float sv = sel[b * SEQ + t];
      float* yr = y + (size_t)(b * SEQ + t) * DM;
#pragma unroll
      for (int j = 0; j < 2; ++j) {
        const int col = n0 + wc * 32 + j * 16 + l16;
        const float bv = (kb == 0) ? ob[col] : 0.f;
        atomicAdd(&yr[col], (acc[i][j][r] + bv) * sv);
      }
    }
  }
}

// ---------------------------------------------------------------------------
extern "C" void kernel_launch(void* const* d_in, const int* in_sizes, int n_in,
                              void* d_out, int out_size, void* d_ws, size_t ws_size,
                              hipStream_t stream) {
  const float* x      = (const float*)d_in[0];
  const float* Wqkv_w = (const float*)d_in[1];
  const float* Wqkv_b = (const float*)d_in[2];
  const float* sel_w  = (const float*)d_in[3];
  const float* sel_b  = (const float*)d_in[4];
  const float* out_w  = (const float*)d_in[5];
  const float* out_b  = (const float*)d_in[6];
  const float* temp   = (const float*)d_in[7];
  float* y = (float*)d_out;

  // workspace layout (bytes, all 16B aligned)
  char* wsb = (char*)d_ws;
  ushort_t* kv     = (ushort_t*)wsb;  wsb += (size_t)BATCH * SEQ * NKV * 2;        // 12.58 MB
  ushort_t* o_part = (ushort_t*)wsb;  wsb += (size_t)24 * NCHUNK * 64 * 64 * 2;    // 6.29 MB
  float*    m_part = (float*)wsb;     wsb += (size_t)24 * NCHUNK * 64 * 4;
  float*    l_part = (float*)wsb;     wsb += (size_t)24 * NCHUNK * 64 * 4;
  float*    sel    = (float*)wsb;     wsb += (size_t)BATCH * SEQ * 4;
  int*      idx    = (int*)wsb;       wsb += 128 * 4;
  int*      idxp   = (int*)wsb;       wsb += 128 * 4;
  ushort_t* ctx_bf = (ushort_t*)wsb;  wsb += (size_t)128 * DM * 2;
  ushort_t* qb     = (ushort_t*)wsb;  wsb += (size_t)128 * DM * 2;
  ushort_t* Xbf    = (ushort_t*)wsb;  wsb += (size_t)BATCH * SEQ * DM * 2;         // 6.29 MB
  ushort_t* Wt     = (ushort_t*)wsb;  wsb += (size_t)N3 * DM * 2;                  // 3.54 MB
  ushort_t* WoT    = (ushort_t*)wsb;  wsb += (size_t)DM * DM * 2;                  // 1.18 MB

  prep_kernel<<<dim3(3328), 256, 0, stream>>>(x, Wqkv_w, out_w, sel_w, sel_b, temp,
                                              Xbf, Wt, WoT, sel, y);
  topk_kernel<<<dim3(BATCH), 256, 0, stream>>>(sel, idx, idxp);
  gemm_kernel<<<dim3(390), 256, 0, stream>>>(Xbf, Wt, Wqkv_b, idxp, kv, qb);
  attn_chunk_kernel<<<dim3(NCHUNK, NH, BATCH), 256, 0, stream>>>(kv, qb, idx, m_part, l_part, o_part);
  attn_combine_kernel<<<dim3(3, NH, BATCH), 256, 0, stream>>>(m_part, l_part, o_part, idx, ctx_bf);
  outproj_kernel<<<dim3(6 * 4), 256, 0, stream>>>(ctx_bf, WoT, out_b, idx, sel, y);
}